// Round 1
// 2527.588 us; speedup vs baseline: 3.0698x; 3.0698x over previous
//
#include <hip/hip_runtime.h>

#define SEQ 2048
#define DH  64
#define NH  16
#define NB  4
#define TQ  8
#define NT  512

// ---------- Kernel 1: per-head K transpose [S][D] -> [D][S] into workspace ----------
__global__ __launch_bounds__(256) void transpose_k(
    const float* __restrict__ K, float* __restrict__ KT)
{
    __shared__ float tile[64][65];
    const int t    = threadIdx.x;
    const int kt   = blockIdx.x & 31;        // k-tile of 64 rows
    const int head = blockIdx.x >> 5;        // b*NH+h, 0..63
    const float* src = K  + (size_t)head * SEQ * DH + (size_t)kt * 64 * DH;
    float*       dst = KT + (size_t)head * SEQ * DH;

    const int r16 = t >> 4;          // 0..15
    const int c4  = (t & 15) * 4;    // 0..60
#pragma unroll
    for (int p = 0; p < 4; ++p) {
        const int row = r16 + p * 16;
        float4 v = *(const float4*)(src + (size_t)row * DH + c4);
        tile[row][c4 + 0] = v.x;
        tile[row][c4 + 1] = v.y;
        tile[row][c4 + 2] = v.z;
        tile[row][c4 + 3] = v.w;
    }
    __syncthreads();
#pragma unroll
    for (int p = 0; p < 4; ++p) {
        const int d = r16 + p * 16;
        float4 v;
        v.x = tile[c4 + 0][d];
        v.y = tile[c4 + 1][d];
        v.z = tile[c4 + 2][d];
        v.w = tile[c4 + 3][d];
        *(float4*)(dst + (size_t)d * SEQ + kt * 64 + c4) = v;
    }
}

// ---------- Kernel 2: attention, 8 q-rows per block of 512 threads ----------
__global__ __launch_bounds__(NT, 4) void attn_fwd(
    const float* __restrict__ Q, const float* __restrict__ KT,
    const float* __restrict__ V, const int* __restrict__ pad,
    float* __restrict__ out_res, float* __restrict__ out_w)
{
    __shared__ __attribute__((aligned(16))) float s_q[TQ][DH];    // 2 KB
    __shared__ float s_red[2][TQ][8];                             // 0.5 KB
    __shared__ __attribute__((aligned(16))) float s_s[TQ][SEQ];   // 64 KB (head reused as s_o)

    const int t     = threadIdx.x;
    const int bid   = blockIdx.x;
    const int qtile = bid & (SEQ / TQ - 1);     // 256 q-tiles per head
    const int h     = (bid >> 8) & (NH - 1);
    const int b     = bid >> 12;
    const int q0    = qtile * TQ;

    const size_t head_off = ((size_t)(b * NH + h)) * SEQ * DH;
    const float* KTh  = KT + head_off;   // [DH][SEQ]
    const float* Vh   = V  + head_off;   // [SEQ][DH]
    const int*   padb = pad + b * SEQ;

    // ---- load Q tile (8 rows x 64), coalesced ----
    {
        const int r = t >> 6, d = t & 63;
        s_q[r][d] = Q[head_off + (size_t)(q0 + r) * DH + d];
    }
    __syncthreads();

    // ---- QK^T: thread owns keys kq..kq+3; coalesced KT loads (lanes along k) ----
    const int  kq  = t * 4;
    const int4 pd4 = *(const int4*)(padb + kq);

    float sc[4][TQ];
#pragma unroll
    for (int i = 0; i < 4; ++i)
#pragma unroll
        for (int r = 0; r < TQ; ++r) sc[i][r] = 0.f;

#pragma unroll 2
    for (int d4 = 0; d4 < 16; ++d4) {
        const float* kp = KTh + (size_t)(d4 * 4) * SEQ + kq;
        const float4 kt0 = *(const float4*)(kp);
        const float4 kt1 = *(const float4*)(kp + SEQ);
        const float4 kt2 = *(const float4*)(kp + 2 * SEQ);
        const float4 kt3 = *(const float4*)(kp + 3 * SEQ);
#pragma unroll
        for (int r = 0; r < TQ; ++r) {
            const float4 qv = *(const float4*)(&s_q[r][d4 * 4]);  // uniform broadcast
            sc[0][r] += kt0.x * qv.x + kt1.x * qv.y + kt2.x * qv.z + kt3.x * qv.w;
            sc[1][r] += kt0.y * qv.x + kt1.y * qv.y + kt2.y * qv.z + kt3.y * qv.w;
            sc[2][r] += kt0.z * qv.x + kt1.z * qv.y + kt2.z * qv.z + kt3.z * qv.w;
            sc[3][r] += kt0.w * qv.x + kt1.w * qv.y + kt2.w * qv.z + kt3.w * qv.w;
        }
    }

    // ---- scale + mask + local max ----
    float lm[TQ];
#pragma unroll
    for (int r = 0; r < TQ; ++r) lm[r] = -3.0e38f;
    const int pdv[4] = {pd4.x, pd4.y, pd4.z, pd4.w};
#pragma unroll
    for (int i = 0; i < 4; ++i) {
        const int k  = kq + i;
        const int pd = pdv[i];
#pragma unroll
        for (int r = 0; r < TQ; ++r) {
            float s = sc[i][r] * 0.125f;                 // 1/sqrt(64)
            const bool masked = ((k > q0 + r) != (pd == 1));  // combined==1 exactly
            if (masked) s = -1.0e9f;
            sc[i][r] = s;
            lm[r] = fmaxf(lm[r], s);
        }
    }

    // ---- row max: wave butterfly, then cross-wave (8 waves) via LDS ----
    const int wv = t >> 6;
#pragma unroll
    for (int r = 0; r < TQ; ++r) {
        float v = lm[r];
#pragma unroll
        for (int off = 32; off > 0; off >>= 1)
            v = fmaxf(v, __shfl_xor(v, off, 64));
        lm[r] = v;
    }
    if ((t & 63) == 0) {
#pragma unroll
        for (int r = 0; r < TQ; ++r) s_red[0][r][wv] = lm[r];
    }
    __syncthreads();

    float m[TQ], lsum[TQ];
#pragma unroll
    for (int r = 0; r < TQ; ++r) {
        float mm = s_red[0][r][0];
#pragma unroll
        for (int w = 1; w < 8; ++w) mm = fmaxf(mm, s_red[0][r][w]);
        m[r]    = mm;
        lsum[r] = 0.f;
    }

    // ---- exp + row sum ----
#pragma unroll
    for (int i = 0; i < 4; ++i)
#pragma unroll
        for (int r = 0; r < TQ; ++r) {
            float e = __expf(sc[i][r] - m[r]);
            sc[i][r] = e;
            lsum[r] += e;
        }
#pragma unroll
    for (int r = 0; r < TQ; ++r) {
        float v = lsum[r];
#pragma unroll
        for (int off = 32; off > 0; off >>= 1)
            v += __shfl_xor(v, off, 64);
        lsum[r] = v;
    }
    if ((t & 63) == 0) {
#pragma unroll
        for (int r = 0; r < TQ; ++r) s_red[1][r][wv] = lsum[r];
    }
    __syncthreads();

    float inv[TQ];
#pragma unroll
    for (int r = 0; r < TQ; ++r) {
        float ss = s_red[1][r][0];
#pragma unroll
        for (int w = 1; w < 8; ++w) ss += s_red[1][r][w];
        inv[r] = 1.0f / ss;
    }

    // ---- normalize: float4 stash to LDS + float4 global store ----
    const size_t wbase = (size_t)bid * TQ * SEQ;
#pragma unroll
    for (int r = 0; r < TQ; ++r) {
        float4 w4;
        w4.x = sc[0][r] * inv[r];
        w4.y = sc[1][r] * inv[r];
        w4.z = sc[2][r] * inv[r];
        w4.w = sc[3][r] * inv[r];
        *(float4*)(&s_s[r][kq]) = w4;
        *(float4*)(&out_w[wbase + (size_t)r * SEQ + kq]) = w4;
    }
    __syncthreads();

    // ---- PV: thread = (chunk c of 64 keys, 4-wide d-group); float4 V loads ----
    const int dg = t & 15;
    const int c  = t >> 4;          // 0..31
    const int d0 = dg * 4;
    float4 oacc[TQ];
#pragma unroll
    for (int r = 0; r < TQ; ++r) oacc[r] = make_float4(0.f, 0.f, 0.f, 0.f);

    const int kb = c * 64;
#pragma unroll 2
    for (int g = 0; g < 16; ++g) {
        const int gg = (g + ((c & 1) << 2)) & 15;   // rotate start: spreads LDS banks
        const int k  = kb + gg * 4;
        const float* vp = Vh + (size_t)k * DH + d0;
        const float4 vv0 = *(const float4*)(vp);
        const float4 vv1 = *(const float4*)(vp + DH);
        const float4 vv2 = *(const float4*)(vp + 2 * DH);
        const float4 vv3 = *(const float4*)(vp + 3 * DH);
#pragma unroll
        for (int r = 0; r < TQ; ++r) {
            const float4 w4 = *(const float4*)(&s_s[r][k]);  // 16-lane broadcast groups
            oacc[r].x += w4.x * vv0.x + w4.y * vv1.x + w4.z * vv2.x + w4.w * vv3.x;
            oacc[r].y += w4.x * vv0.y + w4.y * vv1.y + w4.z * vv2.y + w4.w * vv3.y;
            oacc[r].z += w4.x * vv0.z + w4.y * vv1.z + w4.z * vv2.z + w4.w * vv3.z;
            oacc[r].w += w4.x * vv0.w + w4.y * vv1.w + w4.z * vv2.w + w4.w * vv3.w;
        }
    }

    // reduce the wave's 4 chunks (lane bits 4,5)
#pragma unroll
    for (int r = 0; r < TQ; ++r) {
        oacc[r].x += __shfl_xor(oacc[r].x, 16, 64);
        oacc[r].y += __shfl_xor(oacc[r].y, 16, 64);
        oacc[r].z += __shfl_xor(oacc[r].z, 16, 64);
        oacc[r].w += __shfl_xor(oacc[r].w, 16, 64);
        oacc[r].x += __shfl_xor(oacc[r].x, 32, 64);
        oacc[r].y += __shfl_xor(oacc[r].y, 32, 64);
        oacc[r].z += __shfl_xor(oacc[r].z, 32, 64);
        oacc[r].w += __shfl_xor(oacc[r].w, 32, 64);
    }

    __syncthreads();   // all s_s reads complete before aliased s_o writes
    float (*s_o)[TQ][DH] = (float (*)[TQ][DH])(&s_s[0][0]);  // 16 KB, aliases s_s
    if ((t & 63) < 16) {
#pragma unroll
        for (int r = 0; r < TQ; ++r)
            *(float4*)(&s_o[wv][r][d0]) = oacc[r];
    }
    __syncthreads();

    // ---- final cross-wave sum + store result ----
    {
        const int r = t >> 6;
        const int d = t & 63;
        float o = 0.f;
#pragma unroll
        for (int w = 0; w < 8; ++w) o += s_o[w][r][d];
        out_res[(size_t)(bid * TQ + r) * DH + d] = o;
    }
}

extern "C" void kernel_launch(void* const* d_in, const int* in_sizes, int n_in,
                              void* d_out, int out_size, void* d_ws, size_t ws_size,
                              hipStream_t stream) {
    const float* Q   = (const float*)d_in[0];
    const float* K   = (const float*)d_in[1];
    const float* V   = (const float*)d_in[2];
    const int*   pad = (const int*)d_in[3];
    float* out_res = (float*)d_out;
    float* out_w   = out_res + (size_t)NB * NH * SEQ * DH;
    float* KT      = (float*)d_ws;   // NB*NH*SEQ*DH*4 = 33.5 MB

    transpose_k<<<dim3(NB * NH * (SEQ / 64)), 256, 0, stream>>>(K, KT);
    attn_fwd<<<dim3(NB * NH * (SEQ / TQ)), NT, 0, stream>>>(Q, KT, V, pad, out_res, out_w);
}

// Round 2
// 1718.939 us; speedup vs baseline: 4.5139x; 1.4704x over previous
//
#include <hip/hip_runtime.h>

#define SEQ 2048
#define DH  64
#define NH  16
#define NB  4
#define QT  64
#define KTL 64
#define NT  512
#define NBLK (NB * NH * (SEQ / QT))   // 2048 blocks

typedef short bf16x8 __attribute__((ext_vector_type(8)));
typedef float f32x4  __attribute__((ext_vector_type(4)));

static __device__ __forceinline__ unsigned short f2bf(float x) {
    union { float f; unsigned u; } v; v.f = x;
    unsigned r = v.u + 0x7FFFu + ((v.u >> 16) & 1u);   // RNE
    return (unsigned short)(r >> 16);
}
static __device__ __forceinline__ float bf2f(unsigned short h) {
    union { float f; unsigned u; } v; v.u = ((unsigned)h) << 16;
    return v.f;
}
// XOR-swizzled element index in a [row][64] short tile (T2: kills 32-way conflicts)
static __device__ __forceinline__ int swe(int row, int col) {
    return (row << 6) + (col ^ ((row & 7) << 3));
}

// score MFMAs — MUST be identical in pass 1 and pass 2 (bitwise-equal e)
#define QK_TILE(acc0, acc1)                                                          \
  do {                                                                               \
    bf16x8 b0h[2], b0l[2], b1h[2], b1l[2];                                           \
    _Pragma("unroll") for (int dh = 0; dh < 2; ++dh) {                               \
      const int d0 = dh * 32 + lg * 8;                                               \
      b0h[dh] = *(const bf16x8*)&s_kh[swe(key0, d0)];                                \
      b0l[dh] = *(const bf16x8*)&s_kl[swe(key0, d0)];                                \
      b1h[dh] = *(const bf16x8*)&s_kh[swe(key1, d0)];                                \
      b1l[dh] = *(const bf16x8*)&s_kl[swe(key1, d0)];                                \
    }                                                                                \
    _Pragma("unroll") for (int dh = 0; dh < 2; ++dh) {                               \
      acc0 = __builtin_amdgcn_mfma_f32_16x16x32_bf16(qfh[dh], b0h[dh], acc0, 0,0,0); \
      acc1 = __builtin_amdgcn_mfma_f32_16x16x32_bf16(qfh[dh], b1h[dh], acc1, 0,0,0); \
      acc0 = __builtin_amdgcn_mfma_f32_16x16x32_bf16(qfh[dh], b0l[dh], acc0, 0,0,0); \
      acc1 = __builtin_amdgcn_mfma_f32_16x16x32_bf16(qfh[dh], b1l[dh], acc1, 0,0,0); \
      acc0 = __builtin_amdgcn_mfma_f32_16x16x32_bf16(qfl[dh], b0h[dh], acc0, 0,0,0); \
      acc1 = __builtin_amdgcn_mfma_f32_16x16x32_bf16(qfl[dh], b1h[dh], acc1, 0,0,0); \
    }                                                                                \
  } while (0)

// stage one 64x64 fp32 tile from gptr into swizzled bf16 hi/lo LDS (coalesced)
#define STAGE_ROWS(gptr, dsth, dstl)                                                 \
  do {                                                                               \
    const int rk  = t >> 3;                                                          \
    const int dk0 = (t & 7) * 8;                                                     \
    const float* gp = (gptr) + (size_t)rk * DH + dk0;                                \
    const float4 aa = *(const float4*)gp;                                            \
    const float4 bb = *(const float4*)(gp + 4);                                      \
    float xs[8];                                                                     \
    xs[0]=aa.x; xs[1]=aa.y; xs[2]=aa.z; xs[3]=aa.w;                                  \
    xs[4]=bb.x; xs[5]=bb.y; xs[6]=bb.z; xs[7]=bb.w;                                  \
    bf16x8 hi8, lo8;                                                                 \
    _Pragma("unroll") for (int j = 0; j < 8; ++j) {                                  \
      unsigned short h = f2bf(xs[j]);                                                \
      hi8[j] = (short)h; lo8[j] = (short)f2bf(xs[j] - bf2f(h));                      \
    }                                                                                \
    *(bf16x8*)&(dsth)[swe(rk, dk0)] = hi8;                                           \
    *(bf16x8*)&(dstl)[swe(rk, dk0)] = lo8;                                           \
  } while (0)

__global__ __launch_bounds__(NT, 4) void attn_fwd(
    const float* __restrict__ Q, const float* __restrict__ K,
    const float* __restrict__ V, const int* __restrict__ pad,
    float* __restrict__ out_res, float* __restrict__ out_w)
{
    __shared__ short s_kh[64 * 64], s_kl[64 * 64];   // K tile  [key][d]   bf16 hi/lo
    __shared__ short s_vh[64 * 64], s_vl[64 * 64];   // V^T tile [d][key]  bf16 hi/lo
    __shared__ short s_wh[64 * 64], s_wl[64 * 64];   // W tile  [q][key]   bf16 hi/lo
    __shared__ union QO { short q[2][64 * 64]; float o[64][68]; } s_u;  // Q hi/lo -> O
    __shared__ float s_red[64][2];

    const int t = threadIdx.x;
    int bid = blockIdx.x;
    bid = (bid & 7) * (NBLK / 8) + (bid >> 3);       // XCD-chunked swizzle (bijective)

    const int qtile = bid & (SEQ / QT - 1);          // 32 q-tiles per head
    const int head  = bid >> 5;                      // b*NH + h
    const int q0    = qtile * QT;
    const size_t hoff = (size_t)head * SEQ * DH;
    const size_t woff = (size_t)head * SEQ * SEQ;
    const float* Qg = Q + hoff;
    const float* Kg = K + hoff;
    const float* Vg = V + hoff;
    const int*   padb = pad + (head >> 4) * SEQ;

    const int l  = t & 63;
    const int wq = (t >> 6) & 3;                     // q-strip 0..3 (16 rows each)
    const int wk = t >> 8;                           // k-half  0..1 (32 keys each)
    const int lj = l & 15;
    const int lg = l >> 4;

    // ---- stage Q (64x64) as bf16 hi/lo, then keep fragments in registers ----
    STAGE_ROWS(Qg + (size_t)q0 * DH, s_u.q[0], s_u.q[1]);
    __syncthreads();

    bf16x8 qfh[2], qfl[2];
    {
        const int row = wq * 16 + lj;
#pragma unroll
        for (int dh = 0; dh < 2; ++dh) {
            const int d0 = dh * 32 + lg * 8;
            qfh[dh] = *(const bf16x8*)&s_u.q[0][swe(row, d0)];
            qfl[dh] = *(const bf16x8*)&s_u.q[1][swe(row, d0)];
        }
    }

    const int key0 = wk * 32 + lj;       // B-frag key columns (tile n=0)
    const int key1 = key0 + 16;          // tile n=1
    const int qb   = q0 + wq * 16 + lg * 4;   // first of this lane's 4 q-rows

    // =================== PASS 1: row sums of exp(s) ===================
    float rs[4] = {0.f, 0.f, 0.f, 0.f};
#pragma unroll 1
    for (int kt = 0; kt < SEQ / KTL; ++kt) {
        const int kb = kt * KTL;
        __syncthreads();
        STAGE_ROWS(Kg + (size_t)kb * DH, s_kh, s_kl);
        __syncthreads();

        f32x4 acc0 = {0.f, 0.f, 0.f, 0.f}, acc1 = {0.f, 0.f, 0.f, 0.f};
        QK_TILE(acc0, acc1);

        const int ka0 = kb + key0, ka1 = kb + key1;
        const int pd0 = padb[ka0], pd1 = padb[ka1];
#pragma unroll
        for (int r = 0; r < 4; ++r) {
            const bool m0 = ((ka0 > qb + r) != (pd0 == 1));
            const bool m1 = ((ka1 > qb + r) != (pd1 == 1));
            rs[r] += m0 ? 0.f : __expf(acc0[r] * 0.125f);
            rs[r] += m1 ? 0.f : __expf(acc1[r] * 0.125f);
        }
    }
    // reduce row sums over the 16 key-lanes, combine the two wk halves via LDS
#pragma unroll
    for (int r = 0; r < 4; ++r) {
#pragma unroll
        for (int off = 1; off < 16; off <<= 1)
            rs[r] += __shfl_xor(rs[r], off, 64);
    }
    if (lj == 0) {
#pragma unroll
        for (int r = 0; r < 4; ++r) s_red[wq * 16 + lg * 4 + r][wk] = rs[r];
    }
    __syncthreads();
    float invr[4];
#pragma unroll
    for (int r = 0; r < 4; ++r) {
        const int qq = wq * 16 + lg * 4 + r;
        invr[r] = 1.0f / (s_red[qq][0] + s_red[qq][1]);
    }

    // =================== PASS 2: weights out + PV via MFMA ===================
    f32x4 ov[4] = {{0.f,0.f,0.f,0.f},{0.f,0.f,0.f,0.f},{0.f,0.f,0.f,0.f},{0.f,0.f,0.f,0.f}};
#pragma unroll 1
    for (int kt = 0; kt < SEQ / KTL; ++kt) {
        const int kb = kt * KTL;
        __syncthreads();
        STAGE_ROWS(Kg + (size_t)kb * DH, s_kh, s_kl);
        {   // stage V transposed: thread owns (d, 8 consecutive k) -> b128 LDS writes
            const int dv  = t >> 3;
            const int kv0 = (t & 7) * 8;
            float xs[8];
#pragma unroll
            for (int i = 0; i < 8; ++i)
                xs[i] = Vg[(size_t)(kb + kv0 + i) * DH + dv];
            bf16x8 hi8, lo8;
#pragma unroll
            for (int j = 0; j < 8; ++j) {
                unsigned short h = f2bf(xs[j]);
                hi8[j] = (short)h; lo8[j] = (short)f2bf(xs[j] - bf2f(h));
            }
            *(bf16x8*)&s_vh[swe(dv, kv0)] = hi8;
            *(bf16x8*)&s_vl[swe(dv, kv0)] = lo8;
        }
        __syncthreads();

        f32x4 acc0 = {0.f, 0.f, 0.f, 0.f}, acc1 = {0.f, 0.f, 0.f, 0.f};
        QK_TILE(acc0, acc1);   // identical op order -> e matches pass 1 bitwise

        const int ka0 = kb + key0, ka1 = kb + key1;
        const int pd0 = padb[ka0], pd1 = padb[ka1];
#pragma unroll
        for (int r = 0; r < 4; ++r) {
            const bool m0 = ((ka0 > qb + r) != (pd0 == 1));
            const bool m1 = ((ka1 > qb + r) != (pd1 == 1));
            const float e0 = m0 ? 0.f : __expf(acc0[r] * 0.125f);
            const float e1 = m1 ? 0.f : __expf(acc1[r] * 0.125f);
            const float w0 = e0 * invr[r];
            const float w1 = e1 * invr[r];
            out_w[woff + (size_t)(qb + r) * SEQ + ka0] = w0;
            out_w[woff + (size_t)(qb + r) * SEQ + ka1] = w1;
            const int qloc = wq * 16 + lg * 4 + r;
            unsigned short h0 = f2bf(w0), h1 = f2bf(w1);
            s_wh[swe(qloc, key0)] = (short)h0;
            s_wl[swe(qloc, key0)] = (short)f2bf(w0 - bf2f(h0));
            s_wh[swe(qloc, key1)] = (short)h1;
            s_wl[swe(qloc, key1)] = (short)f2bf(w1 - bf2f(h1));
        }
        __syncthreads();

        // PV: A = W[q][k] frags, B = V^T[d][k] frags, wave covers its 32-key half
        {
            const int qrow = wq * 16 + lj;
            const int kk   = wk * 32 + lg * 8;
            const bf16x8 awh = *(const bf16x8*)&s_wh[swe(qrow, kk)];
            const bf16x8 awl = *(const bf16x8*)&s_wl[swe(qrow, kk)];
            bf16x8 bvh[4], bvl[4];
#pragma unroll
            for (int n = 0; n < 4; ++n) {
                const int d = n * 16 + lj;
                bvh[n] = *(const bf16x8*)&s_vh[swe(d, kk)];
                bvl[n] = *(const bf16x8*)&s_vl[swe(d, kk)];
            }
#pragma unroll
            for (int n = 0; n < 4; ++n)
                ov[n] = __builtin_amdgcn_mfma_f32_16x16x32_bf16(awh, bvh[n], ov[n], 0,0,0);
#pragma unroll
            for (int n = 0; n < 4; ++n)
                ov[n] = __builtin_amdgcn_mfma_f32_16x16x32_bf16(awh, bvl[n], ov[n], 0,0,0);
#pragma unroll
            for (int n = 0; n < 4; ++n)
                ov[n] = __builtin_amdgcn_mfma_f32_16x16x32_bf16(awl, bvh[n], ov[n], 0,0,0);
        }
    }

    // ---- combine the two k-half partial O's, coalesced store ----
    if (wk == 1) {
#pragma unroll
        for (int n = 0; n < 4; ++n)
#pragma unroll
            for (int r = 0; r < 4; ++r)
                s_u.o[wq * 16 + lg * 4 + r][n * 16 + lj] = ov[n][r];
    }
    __syncthreads();
    if (wk == 0) {
#pragma unroll
        for (int n = 0; n < 4; ++n)
#pragma unroll
            for (int r = 0; r < 4; ++r) {
                const int qq = wq * 16 + lg * 4 + r, dd = n * 16 + lj;
                s_u.o[qq][dd] += ov[n][r];
            }
    }
    __syncthreads();
    {
        const int row = t >> 3;
        const int d0  = (t & 7) * 8;
        const float4 v0 = *(const float4*)&s_u.o[row][d0];
        const float4 v1 = *(const float4*)&s_u.o[row][d0 + 4];
        float* op = out_res + hoff + (size_t)(q0 + row) * DH + d0;
        *(float4*)op       = v0;
        *(float4*)(op + 4) = v1;
    }
}

extern "C" void kernel_launch(void* const* d_in, const int* in_sizes, int n_in,
                              void* d_out, int out_size, void* d_ws, size_t ws_size,
                              hipStream_t stream) {
    const float* Q   = (const float*)d_in[0];
    const float* K   = (const float*)d_in[1];
    const float* V   = (const float*)d_in[2];
    const int*   pad = (const int*)d_in[3];
    float* out_res = (float*)d_out;
    float* out_w   = out_res + (size_t)NB * NH * SEQ * DH;

    attn_fwd<<<dim3(NBLK), NT, 0, stream>>>(Q, K, V, pad, out_res, out_w);
}

// Round 3
// 1595.498 us; speedup vs baseline: 4.8632x; 1.0774x over previous
//
#include <hip/hip_runtime.h>

#define SEQ 2048
#define DH  64
#define NH  16
#define NB  4
#define QT  64
#define NT  512
#define NHEADS (NB * NH)               // 64
#define NKT (SEQ / 64)                 // 32 k-tiles
#define NBLK (NHEADS * (SEQ / QT))     // 2048 blocks
#define TILE_ELEMS 4096                // 64x64 shorts

typedef _Float16 f16x8 __attribute__((ext_vector_type(8)));
typedef short    s16x8 __attribute__((ext_vector_type(8)));
typedef float    f32x4 __attribute__((ext_vector_type(4)));

// swizzled element index in a [row][64] short tile (conflict-free b128 reads)
static __device__ __forceinline__ int swe(int row, int col) {
    return (row << 6) + (col ^ ((row & 7) << 3));
}

static __device__ __forceinline__ void gload16(const void* g, void* l) {
    __builtin_amdgcn_global_load_lds(
        (const __attribute__((address_space(1))) void*)g,
        (__attribute__((address_space(3))) void*)l, 16, 0, 0);
}

static __device__ __forceinline__ short f16b(float x) {
    _Float16 h = (_Float16)x;
    return __builtin_bit_cast(short, h);
}

// ---------------- prep: fp32 K,V -> per-tile swizzled f16 hi/lo images ----------------
__global__ __launch_bounds__(256) void prep(
    const float* __restrict__ K, const float* __restrict__ V,
    short* __restrict__ kh, short* __restrict__ kl,
    short* __restrict__ vh, short* __restrict__ vl)
{
    const int t    = threadIdx.x;
    const int kt   = blockIdx.x & (NKT - 1);
    const int head = blockIdx.x >> 5;
    const size_t toff = ((size_t)head * NKT + kt) * TILE_ELEMS;
    const float* Kg = K + ((size_t)head * SEQ + (size_t)kt * 64) * DH;
    const float* Vg = V + ((size_t)head * SEQ + (size_t)kt * 64) * DH;

    {   // K image: [k][d], thread owns (row = t>>2, 16 cols)
        const int row = t >> 2;
        const int c0  = (t & 3) * 16;
        const float4* gp = (const float4*)(Kg + (size_t)row * DH + c0);
        const float4 v0 = gp[0], v1 = gp[1], v2 = gp[2], v3 = gp[3];
        const float x[16] = {v0.x,v0.y,v0.z,v0.w, v1.x,v1.y,v1.z,v1.w,
                             v2.x,v2.y,v2.z,v2.w, v3.x,v3.y,v3.z,v3.w};
        s16x8 hi[2], lo[2];
#pragma unroll
        for (int j = 0; j < 16; ++j) {
            _Float16 h = (_Float16)x[j];
            hi[j >> 3][j & 7] = __builtin_bit_cast(short, h);
            lo[j >> 3][j & 7] = f16b(x[j] - (float)h);
        }
        *(s16x8*)&kh[toff + swe(row, c0)]     = hi[0];
        *(s16x8*)&kh[toff + swe(row, c0 + 8)] = hi[1];
        *(s16x8*)&kl[toff + swe(row, c0)]     = lo[0];
        *(s16x8*)&kl[toff + swe(row, c0 + 8)] = lo[1];
    }
    {   // V^T image: [d][k], thread owns (d = t&63, 8 consecutive k), two k-halves
#pragma unroll
        for (int half = 0; half < 2; ++half) {
            const int d  = t & 63;
            const int k0 = half * 32 + (t >> 6) * 8;
            s16x8 hi8, lo8;
#pragma unroll
            for (int i = 0; i < 8; ++i) {
                float x = Vg[(size_t)(k0 + i) * DH + d];   // coalesced across lanes
                _Float16 h = (_Float16)x;
                hi8[i] = __builtin_bit_cast(short, h);
                lo8[i] = f16b(x - (float)h);
            }
            *(s16x8*)&vh[toff + swe(d, k0)] = hi8;
            *(s16x8*)&vl[toff + swe(d, k0)] = lo8;
        }
    }
}

// score MFMAs — identical op order in pass 1 and pass 2 (bitwise-equal e)
#define QK_TILE(A0, A1) do {                                                         \
  _Pragma("unroll") for (int dh = 0; dh < 2; ++dh) {                                 \
    const int d0 = dh * 32 + lg * 8;                                                 \
    const f16x8 bh = *(const f16x8*)&s_kh[swe(key, d0)];                             \
    const f16x8 bl = *(const f16x8*)&s_kl[swe(key, d0)];                             \
    A0 = __builtin_amdgcn_mfma_f32_16x16x32_f16(qfh[0][dh], bh, A0, 0, 0, 0);        \
    A1 = __builtin_amdgcn_mfma_f32_16x16x32_f16(qfh[1][dh], bh, A1, 0, 0, 0);        \
    A0 = __builtin_amdgcn_mfma_f32_16x16x32_f16(qfh[0][dh], bl, A0, 0, 0, 0);        \
    A1 = __builtin_amdgcn_mfma_f32_16x16x32_f16(qfh[1][dh], bl, A1, 0, 0, 0);        \
    A0 = __builtin_amdgcn_mfma_f32_16x16x32_f16(qfl[0][dh], bh, A0, 0, 0, 0);        \
    A1 = __builtin_amdgcn_mfma_f32_16x16x32_f16(qfl[1][dh], bh, A1, 0, 0, 0);        \
  } } while (0)

__global__ __launch_bounds__(NT, 4) void attn_fwd(
    const float* __restrict__ Q,
    const short* __restrict__ KH, const short* __restrict__ KL,
    const short* __restrict__ VH, const short* __restrict__ VL,
    const int* __restrict__ pad,
    float* __restrict__ out_res, float* __restrict__ out_w)
{
    __shared__ __attribute__((aligned(16))) short s_kh[TILE_ELEMS], s_kl[TILE_ELEMS];
    __shared__ __attribute__((aligned(16))) short s_vh[TILE_ELEMS], s_vl[TILE_ELEMS];
    __shared__ __attribute__((aligned(16))) short s_w [TILE_ELEMS];
    __shared__ __attribute__((aligned(16))) union { short q[2][TILE_ELEMS]; float o[64][68]; } s_u;
    __shared__ float s_red[64][4];

    const int t = threadIdx.x;
    int bid = blockIdx.x;
    bid = (bid & 7) * (NBLK / 8) + (bid >> 3);        // XCD-chunked swizzle (2048%8==0)

    const int qtile = bid & (SEQ / QT - 1);           // 32 q-tiles per head
    const int head  = bid >> 5;                       // b*NH + h
    const int q0    = qtile * QT;
    const size_t hoff = (size_t)head * SEQ * DH;
    const size_t woff = (size_t)head * SEQ * SEQ;
    const int*   padb = pad + (head >> 4) * SEQ;

    const short* khh = KH + (size_t)head * NKT * TILE_ELEMS;
    const short* klh = KL + (size_t)head * NKT * TILE_ELEMS;
    const short* vhh = VH + (size_t)head * NKT * TILE_ELEMS;
    const short* vlh = VL + (size_t)head * NKT * TILE_ELEMS;

    const int l  = t & 63;
    const int w  = t >> 6;       // wave 0..7
    const int wq = w >> 2;       // q-half  0..1 (32 rows)
    const int wk = w & 3;        // key 16-col group 0..3
    const int lj = l & 15;
    const int lg = l >> 4;

    // ---- stage Q (64x64) as f16 hi/lo ----
    {
        const int row = t >> 3;
        const int c0  = (t & 7) * 8;
        const float* gp = Q + hoff + (size_t)(q0 + row) * DH + c0;
        const float4 a = *(const float4*)gp;
        const float4 b = *(const float4*)(gp + 4);
        const float x[8] = {a.x,a.y,a.z,a.w, b.x,b.y,b.z,b.w};
        s16x8 hi8, lo8;
#pragma unroll
        for (int j = 0; j < 8; ++j) {
            _Float16 h = (_Float16)x[j];
            hi8[j] = __builtin_bit_cast(short, h);
            lo8[j] = f16b(x[j] - (float)h);
        }
        *(s16x8*)&s_u.q[0][swe(row, c0)] = hi8;
        *(s16x8*)&s_u.q[1][swe(row, c0)] = lo8;
    }
    __syncthreads();

    f16x8 qfh[2][2], qfl[2][2];
#pragma unroll
    for (int m = 0; m < 2; ++m)
#pragma unroll
        for (int dh = 0; dh < 2; ++dh) {
            const int row = wq * 32 + m * 16 + lj;
            const int d0  = dh * 32 + lg * 8;
            qfh[m][dh] = *(const f16x8*)&s_u.q[0][swe(row, d0)];
            qfl[m][dh] = *(const f16x8*)&s_u.q[1][swe(row, d0)];
        }

    const int key = wk * 16 + lj;            // tile-local key column

    // =================== PASS 1: row sums of exp(s) ===================
    float rs[2][4] = {};
#pragma unroll 1
    for (int kt = 0; kt < NKT; ++kt) {
        __syncthreads();
        {
            const size_t off = (size_t)kt * TILE_ELEMS + (size_t)t * 8;
            gload16(khh + off, &s_kh[w * 512]);
            gload16(klh + off, &s_kl[w * 512]);
        }
        __syncthreads();

        f32x4 a0 = {0.f,0.f,0.f,0.f}, a1 = {0.f,0.f,0.f,0.f};
        QK_TILE(a0, a1);

        const int ka = kt * 64 + key;
        const int pd = padb[ka];
#pragma unroll
        for (int m = 0; m < 2; ++m) {
            const f32x4 av = m ? a1 : a0;
            const int qrow = q0 + wq * 32 + m * 16 + lg * 4;
#pragma unroll
            for (int r = 0; r < 4; ++r) {
                const bool msk = ((ka > qrow + r) != (pd == 1));
                const float s  = msk ? -8.0e9f : av[r];
                rs[m][r] += __expf(s * 0.125f);   // masked -> exp(-1e9) = 0
            }
        }
    }
    // reduce over the 16 key-lanes, then across the 4 wk waves via LDS
#pragma unroll
    for (int m = 0; m < 2; ++m)
#pragma unroll
        for (int r = 0; r < 4; ++r) {
            float v = rs[m][r];
#pragma unroll
            for (int off = 1; off < 16; off <<= 1) v += __shfl_xor(v, off, 64);
            rs[m][r] = v;
        }
    if (lj == 0) {
#pragma unroll
        for (int m = 0; m < 2; ++m)
#pragma unroll
            for (int r = 0; r < 4; ++r)
                s_red[wq * 32 + m * 16 + lg * 4 + r][wk] = rs[m][r];
    }
    __syncthreads();
    float invr[2][4];
#pragma unroll
    for (int m = 0; m < 2; ++m)
#pragma unroll
        for (int r = 0; r < 4; ++r) {
            const int row = wq * 32 + m * 16 + lg * 4 + r;
            invr[m][r] = 1.0f / (s_red[row][0] + s_red[row][1] +
                                 s_red[row][2] + s_red[row][3]);
        }

    // =================== PASS 2: weights out + PV via MFMA ===================
    f32x4 ov[2][2];
#pragma unroll
    for (int m = 0; m < 2; ++m)
#pragma unroll
        for (int n = 0; n < 2; ++n) ov[m][n] = (f32x4){0.f,0.f,0.f,0.f};

    const int wk2   = wk >> 1;           // PV key-half 0..1
    const int dbase = (wk & 1) * 32;     // PV d-half
    const int ks    = wk2 * 32 + lg * 8; // PV k-slice

#pragma unroll 1
    for (int kt = 0; kt < NKT; ++kt) {
        __syncthreads();
        {
            const size_t off = (size_t)kt * TILE_ELEMS + (size_t)t * 8;
            gload16(khh + off, &s_kh[w * 512]);
            gload16(klh + off, &s_kl[w * 512]);
            gload16(vhh + off, &s_vh[w * 512]);
            gload16(vlh + off, &s_vl[w * 512]);
        }
        __syncthreads();

        f32x4 a0 = {0.f,0.f,0.f,0.f}, a1 = {0.f,0.f,0.f,0.f};
        QK_TILE(a0, a1);   // identical op order -> e matches pass 1 bitwise

        const int ka = kt * 64 + key;
        const int pd = padb[ka];
#pragma unroll
        for (int m = 0; m < 2; ++m) {
            const f32x4 av = m ? a1 : a0;
            const int qrowg = q0 + wq * 32 + m * 16 + lg * 4;
            const int qrowl = wq * 32 + m * 16 + lg * 4;
#pragma unroll
            for (int r = 0; r < 4; ++r) {
                const bool msk = ((ka > qrowg + r) != (pd == 1));
                const float s  = msk ? -8.0e9f : av[r];
                const float e  = __expf(s * 0.125f);
                const float wgt = e * invr[m][r];
                out_w[woff + (size_t)(qrowg + r) * SEQ + ka] = wgt;
                s_w[swe(qrowl + r, key)] = f16b(wgt);
            }
        }
        __syncthreads();   // W visible across waves

        // PV: A = W[q][k], B = V^T[d][k]; wave = (wq, key-half wk2, d-half dbase)
        {
            const f16x8 aw0 = *(const f16x8*)&s_w[swe(wq * 32 + lj,      ks)];
            const f16x8 aw1 = *(const f16x8*)&s_w[swe(wq * 32 + 16 + lj, ks)];
            const f16x8 bh0 = *(const f16x8*)&s_vh[swe(dbase + lj,      ks)];
            const f16x8 bh1 = *(const f16x8*)&s_vh[swe(dbase + 16 + lj, ks)];
            const f16x8 bl0 = *(const f16x8*)&s_vl[swe(dbase + lj,      ks)];
            const f16x8 bl1 = *(const f16x8*)&s_vl[swe(dbase + 16 + lj, ks)];
            ov[0][0] = __builtin_amdgcn_mfma_f32_16x16x32_f16(aw0, bh0, ov[0][0], 0,0,0);
            ov[0][1] = __builtin_amdgcn_mfma_f32_16x16x32_f16(aw0, bh1, ov[0][1], 0,0,0);
            ov[1][0] = __builtin_amdgcn_mfma_f32_16x16x32_f16(aw1, bh0, ov[1][0], 0,0,0);
            ov[1][1] = __builtin_amdgcn_mfma_f32_16x16x32_f16(aw1, bh1, ov[1][1], 0,0,0);
            ov[0][0] = __builtin_amdgcn_mfma_f32_16x16x32_f16(aw0, bl0, ov[0][0], 0,0,0);
            ov[0][1] = __builtin_amdgcn_mfma_f32_16x16x32_f16(aw0, bl1, ov[0][1], 0,0,0);
            ov[1][0] = __builtin_amdgcn_mfma_f32_16x16x32_f16(aw1, bl0, ov[1][0], 0,0,0);
            ov[1][1] = __builtin_amdgcn_mfma_f32_16x16x32_f16(aw1, bl1, ov[1][1], 0,0,0);
        }
    }

    // ---- combine the two key-half partial O's, coalesced store ----
    if (wk2 == 0) {
#pragma unroll
        for (int m = 0; m < 2; ++m)
#pragma unroll
            for (int n = 0; n < 2; ++n)
#pragma unroll
                for (int r = 0; r < 4; ++r)
                    s_u.o[wq * 32 + m * 16 + lg * 4 + r][dbase + n * 16 + lj] = ov[m][n][r];
    }
    __syncthreads();
    if (wk2 == 1) {
#pragma unroll
        for (int m = 0; m < 2; ++m)
#pragma unroll
            for (int n = 0; n < 2; ++n)
#pragma unroll
                for (int r = 0; r < 4; ++r)
                    s_u.o[wq * 32 + m * 16 + lg * 4 + r][dbase + n * 16 + lj] += ov[m][n][r];
    }
    __syncthreads();
    {
        const int row = t >> 3;
        const int c0  = (t & 7) * 8;
        const float4 v0 = *(const float4*)&s_u.o[row][c0];
        const float4 v1 = *(const float4*)&s_u.o[row][c0 + 4];
        float* op = out_res + hoff + (size_t)(q0 + row) * DH + c0;
        *(float4*)op       = v0;
        *(float4*)(op + 4) = v1;
    }
}

extern "C" void kernel_launch(void* const* d_in, const int* in_sizes, int n_in,
                              void* d_out, int out_size, void* d_ws, size_t ws_size,
                              hipStream_t stream) {
    const float* Q   = (const float*)d_in[0];
    const float* K   = (const float*)d_in[1];
    const float* V   = (const float*)d_in[2];
    const int*   pad = (const int*)d_in[3];
    float* out_res = (float*)d_out;
    float* out_w   = out_res + (size_t)NB * NH * SEQ * DH;

    const size_t T = (size_t)NHEADS * NKT * TILE_ELEMS;   // shorts per image
    short* kh = (short*)d_ws;
    short* kl = kh + T;
    short* vh = kl + T;
    short* vl = vh + T;                                   // total 67.1 MB

    prep<<<dim3(NHEADS * NKT), 256, 0, stream>>>(K, V, kh, kl, vh, vl);
    attn_fwd<<<dim3(NBLK), NT, 0, stream>>>(Q, kh, kl, vh, vl, pad, out_res, out_w);
}

// Round 4
// 1465.566 us; speedup vs baseline: 5.2943x; 1.0887x over previous
//
#include <hip/hip_runtime.h>

#define SEQ 2048
#define DH  64
#define NH  16
#define NB  4
#define QT  64
#define NT  512
#define NHEADS (NB * NH)               // 64
#define NKT (SEQ / 64)                 // 32 k-tiles
#define NBLK (NHEADS * (SEQ / QT))     // 2048 blocks
#define TILE_ELEMS 4096                // 64x64 shorts

typedef _Float16 f16x8 __attribute__((ext_vector_type(8)));
typedef short    s16x8 __attribute__((ext_vector_type(8)));
typedef float    f32x4 __attribute__((ext_vector_type(4)));

// swizzled element index in a [row][64] short tile (conflict-free b128 reads)
static __device__ __forceinline__ int swe(int row, int col) {
    return (row << 6) + (col ^ ((row & 7) << 3));
}

static __device__ __forceinline__ void gload16(const void* g, void* l) {
    __builtin_amdgcn_global_load_lds(
        (const __attribute__((address_space(1))) void*)g,
        (__attribute__((address_space(3))) void*)l, 16, 0, 0);
}

static __device__ __forceinline__ short f16b(float x) {
    _Float16 h = (_Float16)x;
    return __builtin_bit_cast(short, h);
}

// ---------------- prep: fp32 K,V -> per-tile swizzled f16 hi/lo images + pad bitmask ----------------
__global__ __launch_bounds__(256) void prep(
    const float* __restrict__ K, const float* __restrict__ V,
    const int* __restrict__ pad,
    short* __restrict__ kh, short* __restrict__ kl,
    short* __restrict__ vh, short* __restrict__ vl,
    unsigned* __restrict__ pm)
{
    const int t    = threadIdx.x;
    const int kt   = blockIdx.x & (NKT - 1);
    const int head = blockIdx.x >> 5;
    const size_t toff = ((size_t)head * NKT + kt) * TILE_ELEMS;
    const float* Kg = K + ((size_t)head * SEQ + (size_t)kt * 64) * DH;
    const float* Vg = V + ((size_t)head * SEQ + (size_t)kt * 64) * DH;

    {   // K image: [k][d]
        const int row = t >> 2;
        const int c0  = (t & 3) * 16;
        const float4* gp = (const float4*)(Kg + (size_t)row * DH + c0);
        const float4 v0 = gp[0], v1 = gp[1], v2 = gp[2], v3 = gp[3];
        const float x[16] = {v0.x,v0.y,v0.z,v0.w, v1.x,v1.y,v1.z,v1.w,
                             v2.x,v2.y,v2.z,v2.w, v3.x,v3.y,v3.z,v3.w};
        s16x8 hi[2], lo[2];
#pragma unroll
        for (int j = 0; j < 16; ++j) {
            _Float16 h = (_Float16)x[j];
            hi[j >> 3][j & 7] = __builtin_bit_cast(short, h);
            lo[j >> 3][j & 7] = f16b(x[j] - (float)h);
        }
        *(s16x8*)&kh[toff + swe(row, c0)]     = hi[0];
        *(s16x8*)&kh[toff + swe(row, c0 + 8)] = hi[1];
        *(s16x8*)&kl[toff + swe(row, c0)]     = lo[0];
        *(s16x8*)&kl[toff + swe(row, c0 + 8)] = lo[1];
    }
    {   // V^T image: [d][k]
#pragma unroll
        for (int half = 0; half < 2; ++half) {
            const int d  = t & 63;
            const int k0 = half * 32 + (t >> 6) * 8;
            s16x8 hi8, lo8;
#pragma unroll
            for (int i = 0; i < 8; ++i) {
                float x = Vg[(size_t)(k0 + i) * DH + d];
                _Float16 h = (_Float16)x;
                hi8[i] = __builtin_bit_cast(short, h);
                lo8[i] = f16b(x - (float)h);
            }
            *(s16x8*)&vh[toff + swe(d, k0)] = hi8;
            *(s16x8*)&vl[toff + swe(d, k0)] = lo8;
        }
    }
    if (blockIdx.x == 0) {   // pad bitmask: pm[b*64 + kl] bit kt = pad[b][kt*64+kl]
        const int b = t >> 6, klc = t & 63;
        unsigned mword = 0;
#pragma unroll
        for (int kt2 = 0; kt2 < NKT; ++kt2)
            mword |= (unsigned)(pad[b * SEQ + kt2 * 64 + klc] & 1) << kt2;
        pm[t] = mword;
    }
}

// score MFMAs — identical op order in pass 1 and pass 2 (bitwise-equal e)
#define QK_TILE(kb_, A0, A1) do {                                                    \
  _Pragma("unroll") for (int dh = 0; dh < 2; ++dh) {                                 \
    const int d0_ = dh * 32 + lg * 8;                                                \
    const f16x8 bh = *(const f16x8*)&s_k[kb_][0][swe(key, d0_)];                     \
    const f16x8 bl = *(const f16x8*)&s_k[kb_][1][swe(key, d0_)];                     \
    A0 = __builtin_amdgcn_mfma_f32_16x16x32_f16(qfh[0][dh], bh, A0, 0, 0, 0);        \
    A1 = __builtin_amdgcn_mfma_f32_16x16x32_f16(qfh[1][dh], bh, A1, 0, 0, 0);        \
    A0 = __builtin_amdgcn_mfma_f32_16x16x32_f16(qfh[0][dh], bl, A0, 0, 0, 0);        \
    A1 = __builtin_amdgcn_mfma_f32_16x16x32_f16(qfh[1][dh], bl, A1, 0, 0, 0);        \
    A0 = __builtin_amdgcn_mfma_f32_16x16x32_f16(qfl[0][dh], bh, A0, 0, 0, 0);        \
    A1 = __builtin_amdgcn_mfma_f32_16x16x32_f16(qfl[1][dh], bh, A1, 0, 0, 0);        \
  } } while (0)

#define STAGE_K(buf_, kt_) do {                                                      \
    const size_t o_ = (size_t)(kt_) * TILE_ELEMS + (size_t)t * 8;                    \
    gload16(khh + o_, &s_k[buf_][0][w * 512]);                                       \
    gload16(klh + o_, &s_k[buf_][1][w * 512]);                                       \
} while (0)
#define STAGE_V(buf_, kt_) do {                                                      \
    const size_t o_ = (size_t)(kt_) * TILE_ELEMS + (size_t)t * 8;                    \
    gload16(vhh + o_, &s_vu.v[buf_][0][w * 512]);                                    \
    gload16(vlh + o_, &s_vu.v[buf_][1][w * 512]);                                    \
} while (0)

#define WAIT_BAR(cnt_) do {                                                          \
    asm volatile("s_waitcnt " cnt_ ::: "memory");                                    \
    __builtin_amdgcn_s_barrier();                                                    \
    __builtin_amdgcn_sched_barrier(0);                                               \
} while (0)

__global__ __launch_bounds__(NT, 4) void attn_fwd(
    const float* __restrict__ Q,
    const short* __restrict__ KH, const short* __restrict__ KL,
    const short* __restrict__ VH, const short* __restrict__ VL,
    const unsigned* __restrict__ PM,
    float* __restrict__ out_res, float* __restrict__ out_w)
{
    __shared__ __attribute__((aligned(16))) short s_k[2][2][TILE_ELEMS];   // 32 KB dbuf K hi/lo
    __shared__ union __attribute__((aligned(16))) {
        short v[2][2][TILE_ELEMS];                                         // 32 KB dbuf V^T hi/lo
        short q[2][TILE_ELEMS];                                            // Q staging (prologue)
        float o[64][68];                                                   // O combine (epilogue)
    } s_vu;
    __shared__ __attribute__((aligned(16))) short s_w[TILE_ELEMS];         // 8 KB f16 e-weights
    __shared__ float s_red[64][4];

    const int t = threadIdx.x;
    int bid = blockIdx.x;
    bid = (bid & 7) * (NBLK / 8) + (bid >> 3);        // XCD-chunked swizzle (2048%8==0)

    const int qtile = bid & (SEQ / QT - 1);
    const int head  = bid >> 5;                       // b*NH + h
    const int q0    = qtile * QT;
    const size_t hoff = (size_t)head * SEQ * DH;
    const size_t woff = (size_t)head * SEQ * SEQ;

    const short* khh = KH + (size_t)head * NKT * TILE_ELEMS;
    const short* klh = KL + (size_t)head * NKT * TILE_ELEMS;
    const short* vhh = VH + (size_t)head * NKT * TILE_ELEMS;
    const short* vlh = VL + (size_t)head * NKT * TILE_ELEMS;

    const int l  = t & 63;
    const int w  = t >> 6;       // wave 0..7
    const int wq = w >> 2;       // q-half  0..1 (32 rows)
    const int wk = w & 3;        // key 16-col group 0..3
    const int lj = l & 15;
    const int lg = l >> 4;

    const int key = wk * 16 + lj;                     // tile-local key column
    const unsigned pmask = PM[(head >> 4) * 64 + key];

    // ---- stage Q (64x64) as f16 hi/lo into s_vu.q ----
    {
        const int row = t >> 3;
        const int c0  = (t & 7) * 8;
        const float* gp = Q + hoff + (size_t)(q0 + row) * DH + c0;
        const float4 a = *(const float4*)gp;
        const float4 b = *(const float4*)(gp + 4);
        const float x[8] = {a.x,a.y,a.z,a.w, b.x,b.y,b.z,b.w};
        s16x8 hi8, lo8;
#pragma unroll
        for (int j = 0; j < 8; ++j) {
            _Float16 h = (_Float16)x[j];
            hi8[j] = __builtin_bit_cast(short, h);
            lo8[j] = f16b(x[j] - (float)h);
        }
        *(s16x8*)&s_vu.q[0][swe(row, c0)] = hi8;
        *(s16x8*)&s_vu.q[1][swe(row, c0)] = lo8;
    }
    __syncthreads();

    f16x8 qfh[2][2], qfl[2][2];
#pragma unroll
    for (int m = 0; m < 2; ++m)
#pragma unroll
        for (int dh = 0; dh < 2; ++dh) {
            const int row = wq * 32 + m * 16 + lj;
            const int d0  = dh * 32 + lg * 8;
            qfh[m][dh] = *(const f16x8*)&s_vu.q[0][swe(row, d0)];
            qfl[m][dh] = *(const f16x8*)&s_vu.q[1][swe(row, d0)];
        }
    // Q-frag reads must complete before V staging overwrites s_vu
    asm volatile("s_waitcnt lgkmcnt(0)" ::: "memory");
    __syncthreads();

    const int wk2   = wk >> 1;           // PV key-half
    const int dbase = (wk & 1) * 32;     // PV d-half
    const int ks    = wk2 * 32 + lg * 8; // PV k-slice

    // =============== PASS 1: rowsums + PV with unnormalized f16(e) weights ===============
    float rs[2][4] = {};
    f32x4 ov[2][2];
#pragma unroll
    for (int m = 0; m < 2; ++m)
#pragma unroll
        for (int n = 0; n < 2; ++n) ov[m][n] = (f32x4){0.f,0.f,0.f,0.f};

    STAGE_K(0, 0);
    STAGE_V(0, 0);
    WAIT_BAR("vmcnt(0)");

#pragma unroll 1
    for (int kt = 0; kt < NKT; ++kt) {
        const int cur = kt & 1, nxt = cur ^ 1;
        const int ktn = (kt + 1) & (NKT - 1);
        STAGE_K(nxt, ktn);                 // issue early: latency hides under compute
        STAGE_V(nxt, ktn);

        f32x4 a0 = {0.f,0.f,0.f,0.f}, a1 = {0.f,0.f,0.f,0.f};
        __builtin_amdgcn_s_setprio(1);
        QK_TILE(cur, a0, a1);
        __builtin_amdgcn_s_setprio(0);

        const int ka = kt * 64 + key;
        const int pd = (int)((pmask >> kt) & 1u);
#pragma unroll
        for (int m = 0; m < 2; ++m) {
            const f32x4 av = m ? a1 : a0;
            const int qrow = q0 + wq * 32 + m * 16 + lg * 4;
            const int qloc = wq * 32 + m * 16 + lg * 4;
#pragma unroll
            for (int r = 0; r < 4; ++r) {
                const bool msk = ((ka > qrow + r) != (pd == 1));
                const float s  = msk ? -8.0e9f : av[r];
                const float e  = __expf(s * 0.125f);   // e <= ~e^6, fits f16
                rs[m][r] += e;
                s_w[swe(qloc + r, key)] = f16b(e);
            }
        }
        WAIT_BAR("lgkmcnt(0)");            // W (+nothing else) visible to all waves

        {   // PV on current V buffer with unnormalized weights
            const f16x8 aw0 = *(const f16x8*)&s_w[swe(wq * 32 + lj,      ks)];
            const f16x8 aw1 = *(const f16x8*)&s_w[swe(wq * 32 + 16 + lj, ks)];
            const f16x8 bh0 = *(const f16x8*)&s_vu.v[cur][0][swe(dbase + lj,      ks)];
            const f16x8 bh1 = *(const f16x8*)&s_vu.v[cur][0][swe(dbase + 16 + lj, ks)];
            const f16x8 bl0 = *(const f16x8*)&s_vu.v[cur][1][swe(dbase + lj,      ks)];
            const f16x8 bl1 = *(const f16x8*)&s_vu.v[cur][1][swe(dbase + 16 + lj, ks)];
            __builtin_amdgcn_s_setprio(1);
            ov[0][0] = __builtin_amdgcn_mfma_f32_16x16x32_f16(aw0, bh0, ov[0][0], 0,0,0);
            ov[0][1] = __builtin_amdgcn_mfma_f32_16x16x32_f16(aw0, bh1, ov[0][1], 0,0,0);
            ov[1][0] = __builtin_amdgcn_mfma_f32_16x16x32_f16(aw1, bh0, ov[1][0], 0,0,0);
            ov[1][1] = __builtin_amdgcn_mfma_f32_16x16x32_f16(aw1, bh1, ov[1][1], 0,0,0);
            ov[0][0] = __builtin_amdgcn_mfma_f32_16x16x32_f16(aw0, bl0, ov[0][0], 0,0,0);
            ov[0][1] = __builtin_amdgcn_mfma_f32_16x16x32_f16(aw0, bl1, ov[0][1], 0,0,0);
            ov[1][0] = __builtin_amdgcn_mfma_f32_16x16x32_f16(aw1, bl0, ov[1][0], 0,0,0);
            ov[1][1] = __builtin_amdgcn_mfma_f32_16x16x32_f16(aw1, bl1, ov[1][1], 0,0,0);
            __builtin_amdgcn_s_setprio(0);
        }
        WAIT_BAR("vmcnt(0)");              // next tile's staging landed; buffers swap
    }

    // ---- rowsum reduction -> invr ----
#pragma unroll
    for (int m = 0; m < 2; ++m)
#pragma unroll
        for (int r = 0; r < 4; ++r) {
            float v = rs[m][r];
#pragma unroll
            for (int off = 1; off < 16; off <<= 1) v += __shfl_xor(v, off, 64);
            rs[m][r] = v;
        }
    if (lj == 0) {
#pragma unroll
        for (int m = 0; m < 2; ++m)
#pragma unroll
            for (int r = 0; r < 4; ++r)
                s_red[wq * 32 + m * 16 + lg * 4 + r][wk] = rs[m][r];
    }
    __syncthreads();
    float invr[2][4];
#pragma unroll
    for (int m = 0; m < 2; ++m)
#pragma unroll
        for (int r = 0; r < 4; ++r) {
            const int row = wq * 32 + m * 16 + lg * 4 + r;
            invr[m][r] = 1.0f / (s_red[row][0] + s_red[row][1] +
                                 s_red[row][2] + s_red[row][3]);
        }

    // ---- scale O by invr, combine key-halves, store out_res ----
#pragma unroll
    for (int m = 0; m < 2; ++m)
#pragma unroll
        for (int n = 0; n < 2; ++n)
#pragma unroll
            for (int r = 0; r < 4; ++r) ov[m][n][r] *= invr[m][r];

    if (wk2 == 0) {
#pragma unroll
        for (int m = 0; m < 2; ++m)
#pragma unroll
            for (int n = 0; n < 2; ++n)
#pragma unroll
                for (int r = 0; r < 4; ++r)
                    s_vu.o[wq * 32 + m * 16 + lg * 4 + r][dbase + n * 16 + lj] = ov[m][n][r];
    }
    __syncthreads();
    if (wk2 == 1) {
#pragma unroll
        for (int m = 0; m < 2; ++m)
#pragma unroll
            for (int n = 0; n < 2; ++n)
#pragma unroll
                for (int r = 0; r < 4; ++r)
                    s_vu.o[wq * 32 + m * 16 + lg * 4 + r][dbase + n * 16 + lj] += ov[m][n][r];
    }
    __syncthreads();
    {
        const int row = t >> 3;
        const int c0  = (t & 7) * 8;
        const float4 v0 = *(const float4*)&s_vu.o[row][c0];
        const float4 v1 = *(const float4*)&s_vu.o[row][c0 + 4];
        float* op = out_res + hoff + (size_t)(q0 + row) * DH + c0;
        *(float4*)op       = v0;
        *(float4*)(op + 4) = v1;
    }

    // =============== PASS 2: recompute e (bitwise-identical), store normalized W ===============
    // s_k[0] already holds tile 0 (staged at pass-1 kt=31, waited+barriered).
#pragma unroll 1
    for (int kt = 0; kt < NKT; ++kt) {
        const int cur = kt & 1, nxt = cur ^ 1;
        STAGE_K(nxt, (kt + 1) & (NKT - 1));

        f32x4 a0 = {0.f,0.f,0.f,0.f}, a1 = {0.f,0.f,0.f,0.f};
        __builtin_amdgcn_s_setprio(1);
        QK_TILE(cur, a0, a1);              // same order as pass 1 -> bitwise-equal e
        __builtin_amdgcn_s_setprio(0);

        const int ka = kt * 64 + key;
        const int pd = (int)((pmask >> kt) & 1u);
#pragma unroll
        for (int m = 0; m < 2; ++m) {
            const f32x4 av = m ? a1 : a0;
            const int qrow = q0 + wq * 32 + m * 16 + lg * 4;
#pragma unroll
            for (int r = 0; r < 4; ++r) {
                const bool msk = ((ka > qrow + r) != (pd == 1));
                const float s  = msk ? -8.0e9f : av[r];
                const float e  = __expf(s * 0.125f);
                out_w[woff + (size_t)(qrow + r) * SEQ + ka] = e * invr[m][r];
            }
        }
        // 2 gloads issued before the 8 stores -> vmcnt(8) guarantees gloads done
        // without draining the store queue.
        WAIT_BAR("vmcnt(8)");
    }
}

extern "C" void kernel_launch(void* const* d_in, const int* in_sizes, int n_in,
                              void* d_out, int out_size, void* d_ws, size_t ws_size,
                              hipStream_t stream) {
    const float* Q   = (const float*)d_in[0];
    const float* K   = (const float*)d_in[1];
    const float* V   = (const float*)d_in[2];
    const int*   pad = (const int*)d_in[3];
    float* out_res = (float*)d_out;
    float* out_w   = out_res + (size_t)NB * NH * SEQ * DH;

    const size_t T = (size_t)NHEADS * NKT * TILE_ELEMS;   // shorts per image
    short* kh = (short*)d_ws;
    short* kl = kh + T;
    short* vh = kl + T;
    short* vl = vh + T;
    unsigned* pm = (unsigned*)(vl + T);                   // 1 KB pad bitmask

    prep<<<dim3(NHEADS * NKT), 256, 0, stream>>>(K, V, pad, kh, kl, vh, vl, pm);
    attn_fwd<<<dim3(NBLK), NT, 0, stream>>>(Q, kh, kl, vh, vl, pm, out_res, out_w);
}

// Round 5
// 1376.158 us; speedup vs baseline: 5.6383x; 1.0650x over previous
//
#include <hip/hip_runtime.h>

#define SEQ 2048
#define DH  64
#define NH  16
#define NB  4
#define QT  64
#define NT  512
#define NHEADS (NB * NH)               // 64
#define NKT (SEQ / 64)                 // 32 k-tiles
#define NBLK (NHEADS * (SEQ / QT))     // 2048 blocks
#define TILE_ELEMS 4096                // 64x64 shorts

typedef _Float16 f16x8 __attribute__((ext_vector_type(8)));
typedef short    s16x8 __attribute__((ext_vector_type(8)));
typedef float    f32x4 __attribute__((ext_vector_type(4)));

// swizzled element index in a [row][64] short tile (conflict-free b128 reads)
static __device__ __forceinline__ int swe(int row, int col) {
    return (row << 6) + (col ^ ((row & 7) << 3));
}

static __device__ __forceinline__ void gload16(const void* g, void* l) {
    __builtin_amdgcn_global_load_lds(
        (const __attribute__((address_space(1))) void*)g,
        (__attribute__((address_space(3))) void*)l, 16, 0, 0);
}

static __device__ __forceinline__ short f16b(float x) {
    _Float16 h = (_Float16)x;
    return __builtin_bit_cast(short, h);
}

// ---------------- prep: fp32 K,V -> per-tile swizzled f16 hi/lo images + pad bitmask ----------------
__global__ __launch_bounds__(256) void prep(
    const float* __restrict__ K, const float* __restrict__ V,
    const int* __restrict__ pad,
    short* __restrict__ kh, short* __restrict__ kl,
    short* __restrict__ vh, short* __restrict__ vl,
    unsigned* __restrict__ pm)
{
    const int t    = threadIdx.x;
    const int kt   = blockIdx.x & (NKT - 1);
    const int head = blockIdx.x >> 5;
    const size_t toff = ((size_t)head * NKT + kt) * TILE_ELEMS;
    const float* Kg = K + ((size_t)head * SEQ + (size_t)kt * 64) * DH;
    const float* Vg = V + ((size_t)head * SEQ + (size_t)kt * 64) * DH;

    {   // K image: [k][d]
        const int row = t >> 2;
        const int c0  = (t & 3) * 16;
        const float4* gp = (const float4*)(Kg + (size_t)row * DH + c0);
        const float4 v0 = gp[0], v1 = gp[1], v2 = gp[2], v3 = gp[3];
        const float x[16] = {v0.x,v0.y,v0.z,v0.w, v1.x,v1.y,v1.z,v1.w,
                             v2.x,v2.y,v2.z,v2.w, v3.x,v3.y,v3.z,v3.w};
        s16x8 hi[2], lo[2];
#pragma unroll
        for (int j = 0; j < 16; ++j) {
            _Float16 h = (_Float16)x[j];
            hi[j >> 3][j & 7] = __builtin_bit_cast(short, h);
            lo[j >> 3][j & 7] = f16b(x[j] - (float)h);
        }
        *(s16x8*)&kh[toff + swe(row, c0)]     = hi[0];
        *(s16x8*)&kh[toff + swe(row, c0 + 8)] = hi[1];
        *(s16x8*)&kl[toff + swe(row, c0)]     = lo[0];
        *(s16x8*)&kl[toff + swe(row, c0 + 8)] = lo[1];
    }
    {   // V^T image: [d][k]
#pragma unroll
        for (int half = 0; half < 2; ++half) {
            const int d  = t & 63;
            const int k0 = half * 32 + (t >> 6) * 8;
            s16x8 hi8, lo8;
#pragma unroll
            for (int i = 0; i < 8; ++i) {
                float x = Vg[(size_t)(k0 + i) * DH + d];
                _Float16 h = (_Float16)x;
                hi8[i] = __builtin_bit_cast(short, h);
                lo8[i] = f16b(x - (float)h);
            }
            *(s16x8*)&vh[toff + swe(d, k0)] = hi8;
            *(s16x8*)&vl[toff + swe(d, k0)] = lo8;
        }
    }
    if (blockIdx.x == 0) {   // pad bitmask: pm[b*64 + kl] bit kt = pad[b][kt*64+kl]
        const int b = t >> 6, klc = t & 63;
        unsigned mword = 0;
#pragma unroll
        for (int kt2 = 0; kt2 < NKT; ++kt2)
            mword |= (unsigned)(pad[b * SEQ + kt2 * 64 + klc] & 1) << kt2;
        pm[t] = mword;
    }
}

// score MFMAs — identical op order in pass 1 and pass 2 (bitwise-equal e)
#define QK_TILE(kb_, A0, A1) do {                                                    \
  _Pragma("unroll") for (int dh = 0; dh < 2; ++dh) {                                 \
    const int d0_ = dh * 32 + lg * 8;                                                \
    const f16x8 bh = *(const f16x8*)&s_k[kb_][0][swe(key, d0_)];                     \
    const f16x8 bl = *(const f16x8*)&s_k[kb_][1][swe(key, d0_)];                     \
    A0 = __builtin_amdgcn_mfma_f32_16x16x32_f16(qfh[0][dh], bh, A0, 0, 0, 0);        \
    A1 = __builtin_amdgcn_mfma_f32_16x16x32_f16(qfh[1][dh], bh, A1, 0, 0, 0);        \
    A0 = __builtin_amdgcn_mfma_f32_16x16x32_f16(qfh[0][dh], bl, A0, 0, 0, 0);        \
    A1 = __builtin_amdgcn_mfma_f32_16x16x32_f16(qfh[1][dh], bl, A1, 0, 0, 0);        \
    A0 = __builtin_amdgcn_mfma_f32_16x16x32_f16(qfl[0][dh], bh, A0, 0, 0, 0);        \
    A1 = __builtin_amdgcn_mfma_f32_16x16x32_f16(qfl[1][dh], bh, A1, 0, 0, 0);        \
  } } while (0)

// PV(tile prv): A = W[q][k] frags, B = V^T[d][k] frags
#define PV_TILE(prv_) do {                                                           \
    const f16x8 aw0 = *(const f16x8*)&s_wq.w[prv_][swe(wq * 32 + lj,      ks)];      \
    const f16x8 aw1 = *(const f16x8*)&s_wq.w[prv_][swe(wq * 32 + 16 + lj, ks)];      \
    const f16x8 bh0 = *(const f16x8*)&s_vo.v[prv_][0][swe(dbase + lj,      ks)];     \
    const f16x8 bh1 = *(const f16x8*)&s_vo.v[prv_][0][swe(dbase + 16 + lj, ks)];     \
    const f16x8 bl0 = *(const f16x8*)&s_vo.v[prv_][1][swe(dbase + lj,      ks)];     \
    const f16x8 bl1 = *(const f16x8*)&s_vo.v[prv_][1][swe(dbase + 16 + lj, ks)];     \
    __builtin_amdgcn_s_setprio(1);                                                   \
    ov[0][0] = __builtin_amdgcn_mfma_f32_16x16x32_f16(aw0, bh0, ov[0][0], 0,0,0);    \
    ov[0][1] = __builtin_amdgcn_mfma_f32_16x16x32_f16(aw0, bh1, ov[0][1], 0,0,0);    \
    ov[1][0] = __builtin_amdgcn_mfma_f32_16x16x32_f16(aw1, bh0, ov[1][0], 0,0,0);    \
    ov[1][1] = __builtin_amdgcn_mfma_f32_16x16x32_f16(aw1, bh1, ov[1][1], 0,0,0);    \
    ov[0][0] = __builtin_amdgcn_mfma_f32_16x16x32_f16(aw0, bl0, ov[0][0], 0,0,0);    \
    ov[0][1] = __builtin_amdgcn_mfma_f32_16x16x32_f16(aw0, bl1, ov[0][1], 0,0,0);    \
    ov[1][0] = __builtin_amdgcn_mfma_f32_16x16x32_f16(aw1, bl0, ov[1][0], 0,0,0);    \
    ov[1][1] = __builtin_amdgcn_mfma_f32_16x16x32_f16(aw1, bl1, ov[1][1], 0,0,0);    \
    __builtin_amdgcn_s_setprio(0);                                                   \
} while (0)

#define STAGE_K(buf_, kt_) do {                                                      \
    const size_t o_ = (size_t)(kt_) * TILE_ELEMS + (size_t)t * 8;                    \
    gload16(khh + o_, &s_k[buf_][0][w * 512]);                                       \
    gload16(klh + o_, &s_k[buf_][1][w * 512]);                                       \
} while (0)
#define STAGE_V(buf_, kt_) do {                                                      \
    const size_t o_ = (size_t)(kt_) * TILE_ELEMS + (size_t)t * 8;                    \
    gload16(vhh + o_, &s_vo.v[buf_][0][w * 512]);                                    \
    gload16(vlh + o_, &s_vo.v[buf_][1][w * 512]);                                    \
} while (0)

// per-wave drain of MY loads/LDS-ops, then block-wide barrier -> staged data visible
#define PIPE_BAR(cnt_) do {                                                          \
    asm volatile("s_waitcnt " cnt_ ::: "memory");                                    \
    __builtin_amdgcn_s_barrier();                                                    \
    __builtin_amdgcn_sched_barrier(0);                                               \
} while (0)

__global__ __launch_bounds__(NT, 4) void attn_fwd(
    const float* __restrict__ Q,
    const short* __restrict__ KH, const short* __restrict__ KL,
    const short* __restrict__ VH, const short* __restrict__ VL,
    const unsigned* __restrict__ PM,
    float* __restrict__ out_res, float* __restrict__ out_w)
{
    __shared__ __attribute__((aligned(16))) short s_k[2][2][TILE_ELEMS];  // 32 KB K dbuf hi/lo
    __shared__ union __attribute__((aligned(16))) {
        short v[2][2][TILE_ELEMS];                 // 32 KB V^T dbuf hi/lo
        float o[64][68];                           // 17.4 KB O combine (epilogue only)
    } s_vo;
    __shared__ union __attribute__((aligned(16))) {
        short w[2][TILE_ELEMS];                    // 16 KB W dbuf (f16 e-weights)
        short q[2][TILE_ELEMS];                    // Q staging (prologue only)
    } s_wq;
    // s_red aliases dead W(30) buffer at reduction time (first 1 KB of w[0])
    float (*s_red)[4] = reinterpret_cast<float (*)[4]>(&s_wq.w[0][0]);

    const int t = threadIdx.x;
    int bid = blockIdx.x;
    bid = (bid & 7) * (NBLK / 8) + (bid >> 3);        // XCD-chunked swizzle (2048%8==0)

    const int qtile = bid & (SEQ / QT - 1);
    const int head  = bid >> 5;                       // b*NH + h
    const int q0    = qtile * QT;
    const size_t hoff = (size_t)head * SEQ * DH;
    const size_t woff = (size_t)head * SEQ * SEQ;

    const short* khh = KH + (size_t)head * NKT * TILE_ELEMS;
    const short* klh = KL + (size_t)head * NKT * TILE_ELEMS;
    const short* vhh = VH + (size_t)head * NKT * TILE_ELEMS;
    const short* vlh = VL + (size_t)head * NKT * TILE_ELEMS;

    const int l  = t & 63;
    const int w  = t >> 6;       // wave 0..7
    const int wq = w >> 2;       // q-half  0..1 (32 rows)
    const int wk = w & 3;        // key 16-col group 0..3
    const int lj = l & 15;
    const int lg = l >> 4;

    const int key = wk * 16 + lj;                     // tile-local key column
    const unsigned pmask = PM[(head >> 4) * 64 + key];

    const int wk2   = wk >> 1;           // PV key-half
    const int dbase = (wk & 1) * 32;     // PV d-half
    const int ks    = wk2 * 32 + lg * 8; // PV k-slice

    STAGE_K(0, 0);                       // issue early; drained at loop-top kt=0

    // ---- stage Q (64x64) as f16 hi/lo into s_wq.q ----
    {
        const int row = t >> 3;
        const int c0  = (t & 7) * 8;
        const float* gp = Q + hoff + (size_t)(q0 + row) * DH + c0;
        const float4 a = *(const float4*)gp;
        const float4 b = *(const float4*)(gp + 4);
        const float x[8] = {a.x,a.y,a.z,a.w, b.x,b.y,b.z,b.w};
        s16x8 hi8, lo8;
#pragma unroll
        for (int j = 0; j < 8; ++j) {
            _Float16 h = (_Float16)x[j];
            hi8[j] = __builtin_bit_cast(short, h);
            lo8[j] = f16b(x[j] - (float)h);
        }
        *(s16x8*)&s_wq.q[0][swe(row, c0)] = hi8;
        *(s16x8*)&s_wq.q[1][swe(row, c0)] = lo8;
    }
    __syncthreads();

    f16x8 qfh[2][2], qfl[2][2];
#pragma unroll
    for (int m = 0; m < 2; ++m)
#pragma unroll
        for (int dh = 0; dh < 2; ++dh) {
            const int row = wq * 32 + m * 16 + lj;
            const int d0  = dh * 32 + lg * 8;
            qfh[m][dh] = *(const f16x8*)&s_wq.q[0][swe(row, d0)];
            qfl[m][dh] = *(const f16x8*)&s_wq.q[1][swe(row, d0)];
        }
    // all waves' Q-frag reads must retire before W writes overwrite the region
    asm volatile("s_waitcnt lgkmcnt(0)" ::: "memory");
    __syncthreads();

    // =============== PASS 1: P-lag pipeline — ONE barrier per tile ===============
    // iter t: [drain+barrier] issue V(t),K(t+1) | QK(t) | exp->W(t) | PV(t-1)
    float rs[2][4] = {};
    f32x4 ov[2][2];
#pragma unroll
    for (int m = 0; m < 2; ++m)
#pragma unroll
        for (int n = 0; n < 2; ++n) ov[m][n] = (f32x4){0.f,0.f,0.f,0.f};

#pragma unroll 1
    for (int kt = 0; kt < NKT; ++kt) {
        const int cur = kt & 1, prv = cur ^ 1;
        // all outstanding loads are exactly {K(kt), V(kt-1)} -> needed now;
        // latency was hidden across the previous full iteration.
        PIPE_BAR("vmcnt(0) lgkmcnt(0)");
        STAGE_V(cur, kt);
        STAGE_K(prv, (kt + 1) & (NKT - 1));

        f32x4 a0 = {0.f,0.f,0.f,0.f}, a1 = {0.f,0.f,0.f,0.f};
        __builtin_amdgcn_s_setprio(1);
        QK_TILE(cur, a0, a1);
        __builtin_amdgcn_s_setprio(0);

        const int ka = kt * 64 + key;
        const int pd = (int)((pmask >> kt) & 1u);
#pragma unroll
        for (int m = 0; m < 2; ++m) {
            const f32x4 av = m ? a1 : a0;
            const int qrow = q0 + wq * 32 + m * 16 + lg * 4;
            const int qloc = wq * 32 + m * 16 + lg * 4;
#pragma unroll
            for (int r = 0; r < 4; ++r) {
                const bool msk = ((ka > qrow + r) != (pd == 1));
                const float s  = msk ? -8.0e9f : av[r];
                const float e  = __expf(s * 0.125f);   // e <= ~e^6, fits f16
                rs[m][r] += e;
                s_wq.w[cur][swe(qloc + r, key)] = f16b(e);
            }
        }

        if (kt > 0) PV_TILE(prv);      // previous tile: W/V visible via top barrier
    }
    PIPE_BAR("vmcnt(0) lgkmcnt(0)");    // drains V(31) and K(0)-for-pass-2
    PV_TILE(1);                         // PV(31): prv = 31&1 = 1

    // ---- rowsum reduction -> invr (s_red aliases dead w[0]) ----
#pragma unroll
    for (int m = 0; m < 2; ++m)
#pragma unroll
        for (int r = 0; r < 4; ++r) {
            float v = rs[m][r];
#pragma unroll
            for (int off = 1; off < 16; off <<= 1) v += __shfl_xor(v, off, 64);
            rs[m][r] = v;
        }
    if (lj == 0) {
#pragma unroll
        for (int m = 0; m < 2; ++m)
#pragma unroll
            for (int r = 0; r < 4; ++r)
                s_red[wq * 32 + m * 16 + lg * 4 + r][wk] = rs[m][r];
    }
    __syncthreads();
    float invr[2][4];
#pragma unroll
    for (int m = 0; m < 2; ++m)
#pragma unroll
        for (int r = 0; r < 4; ++r) {
            const int row = wq * 32 + m * 16 + lg * 4 + r;
            invr[m][r] = 1.0f / (s_red[row][0] + s_red[row][1] +
                                 s_red[row][2] + s_red[row][3]);
        }

    // ---- scale O by invr, combine key-halves (o aliases v region), store out_res ----
#pragma unroll
    for (int m = 0; m < 2; ++m)
#pragma unroll
        for (int n = 0; n < 2; ++n)
#pragma unroll
            for (int r = 0; r < 4; ++r) ov[m][n][r] *= invr[m][r];

    if (wk2 == 0) {
#pragma unroll
        for (int m = 0; m < 2; ++m)
#pragma unroll
            for (int n = 0; n < 2; ++n)
#pragma unroll
                for (int r = 0; r < 4; ++r)
                    s_vo.o[wq * 32 + m * 16 + lg * 4 + r][dbase + n * 16 + lj] = ov[m][n][r];
    }
    __syncthreads();
    if (wk2 == 1) {
#pragma unroll
        for (int m = 0; m < 2; ++m)
#pragma unroll
            for (int n = 0; n < 2; ++n)
#pragma unroll
                for (int r = 0; r < 4; ++r)
                    s_vo.o[wq * 32 + m * 16 + lg * 4 + r][dbase + n * 16 + lj] += ov[m][n][r];
    }
    __syncthreads();
    {
        const int row = t >> 3;
        const int c0  = (t & 7) * 8;
        const float4 v0 = *(const float4*)&s_vo.o[row][c0];
        const float4 v1 = *(const float4*)&s_vo.o[row][c0 + 4];
        float* op = out_res + hoff + (size_t)(q0 + row) * DH + c0;
        *(float4*)op       = v0;
        *(float4*)(op + 4) = v1;
    }

    // =============== PASS 2: recompute e (bitwise-identical), store normalized W ===============
    // s_k[0] already holds tile 0 (staged at pass-1 kt=31, drained+barriered).
#pragma unroll 1
    for (int kt = 0; kt < NKT; ++kt) {
        const int cur = kt & 1, nxt = cur ^ 1;
        // outstanding at top: K(kt)[2 oldest] + out_w stores[8] -> vmcnt(8) retires K(kt)
        PIPE_BAR("vmcnt(8)");
        STAGE_K(nxt, (kt + 1) & (NKT - 1));

        f32x4 a0 = {0.f,0.f,0.f,0.f}, a1 = {0.f,0.f,0.f,0.f};
        __builtin_amdgcn_s_setprio(1);
        QK_TILE(cur, a0, a1);              // same order as pass 1 -> bitwise-equal e
        __builtin_amdgcn_s_setprio(0);

        const int ka = kt * 64 + key;
        const int pd = (int)((pmask >> kt) & 1u);
#pragma unroll
        for (int m = 0; m < 2; ++m) {
            const f32x4 av = m ? a1 : a0;
            const int qrow = q0 + wq * 32 + m * 16 + lg * 4;
#pragma unroll
            for (int r = 0; r < 4; ++r) {
                const bool msk = ((ka > qrow + r) != (pd == 1));
                const float s  = msk ? -8.0e9f : av[r];
                const float e  = __expf(s * 0.125f);
                __builtin_nontemporal_store(e * invr[m][r],
                    &out_w[woff + (size_t)(qrow + r) * SEQ + ka]);
            }
        }
    }
}

extern "C" void kernel_launch(void* const* d_in, const int* in_sizes, int n_in,
                              void* d_out, int out_size, void* d_ws, size_t ws_size,
                              hipStream_t stream) {
    const float* Q   = (const float*)d_in[0];
    const float* K   = (const float*)d_in[1];
    const float* V   = (const float*)d_in[2];
    const int*   pad = (const int*)d_in[3];
    float* out_res = (float*)d_out;
    float* out_w   = out_res + (size_t)NB * NH * SEQ * DH;

    const size_t T = (size_t)NHEADS * NKT * TILE_ELEMS;   // shorts per image
    short* kh = (short*)d_ws;
    short* kl = kh + T;
    short* vh = kl + T;
    short* vl = vh + T;
    unsigned* pm = (unsigned*)(vl + T);                   // 1 KB pad bitmask

    prep<<<dim3(NHEADS * NKT), 256, 0, stream>>>(K, V, pad, kh, kl, vh, vl, pm);
    attn_fwd<<<dim3(NBLK), NT, 0, stream>>>(Q, kh, kl, vh, vl, pm, out_res, out_w);
}

// Round 7
// 1362.167 us; speedup vs baseline: 5.6962x; 1.0103x over previous
//
#include <hip/hip_runtime.h>

#define SEQ 2048
#define DH  64
#define NH  16
#define NB  4
#define NHEADS (NB * NH)            // 64
#define NKT 32                      // k-tiles of 64 keys
#define QT  32                      // q-rows per block
#define NQT (SEQ / QT)              // 64 q-tiles per head
#define NBLK (NHEADS * NQT)         // 4096 blocks
#define KTILE_SH 8192               // shorts per K/V tile image (64x64 hi+lo)
#define QTILE_SH 4096               // shorts per Q tile image (32x64 hi+lo)

typedef _Float16 f16x8 __attribute__((ext_vector_type(8)));
typedef _Float16 f16x4 __attribute__((ext_vector_type(4)));
typedef short    s16x8 __attribute__((ext_vector_type(8)));
typedef float    f32x4 __attribute__((ext_vector_type(4)));

#define MF32(a,b,c) __builtin_amdgcn_mfma_f32_16x16x32_f16(a,b,c,0,0,0)
#define MF16(a,b,c) __builtin_amdgcn_mfma_f32_16x16x16f16(a,b,c,0,0,0)

static __device__ __forceinline__ short f16b(float x) {
    _Float16 h = (_Float16)x;
    return __builtin_bit_cast(short, h);
}

// ------------- prep: pack Q,K,V into fragment-ordered f16 hi/lo images -------------
// kimg tile: [kg 4][dh 2][hl 2][lane 64][8]   (A-frag of swapped QK: row=key=lj, k=d)
// qimg tile: [m 2][dh 2][hl 2][lane 64][8]    (B-frag: col=q=lj, k=d)
// vimg tile: [kc 4][dt 4][lane 64][hi 4 | lo 4]  (B-frag of PV: col=d=lj, k=lg*4+j)
__global__ __launch_bounds__(256) void prep(
    const float* __restrict__ Q, const float* __restrict__ K,
    const float* __restrict__ V, const int* __restrict__ pad,
    short* __restrict__ qimg, short* __restrict__ kimg,
    short* __restrict__ vimg, unsigned* __restrict__ pm)
{
    const int t    = threadIdx.x;
    const int kt   = blockIdx.x & (NKT - 1);
    const int head = blockIdx.x >> 5;
    const size_t rowbase = ((size_t)head * SEQ + (size_t)kt * 64) * DH;

    {   // ---- K and Q frag-pack: thread owns (row = t>>2, 16 cols) ----
        const int row = t >> 2;
        const int c0  = (t & 3) * 16;
        const int lj  = row & 15;

        // K
        {
            const float4* gp = (const float4*)(K + rowbase + (size_t)row * DH + c0);
            const float4 v0 = gp[0], v1 = gp[1], v2 = gp[2], v3 = gp[3];
            const float x[16] = {v0.x,v0.y,v0.z,v0.w, v1.x,v1.y,v1.z,v1.w,
                                 v2.x,v2.y,v2.z,v2.w, v3.x,v3.y,v3.z,v3.w};
            short* tb = kimg + ((size_t)head * NKT + kt) * KTILE_SH + (row >> 4) * 2048;
#pragma unroll
            for (int cg = 0; cg < 2; ++cg) {
                const int col0 = c0 + cg * 8;
                const int dh = col0 >> 5, lg = (col0 & 31) >> 3;
                s16x8 hi8, lo8;
#pragma unroll
                for (int j = 0; j < 8; ++j) {
                    const float xv = x[cg * 8 + j];
                    _Float16 h = (_Float16)xv;
                    hi8[j] = __builtin_bit_cast(short, h);
                    lo8[j] = f16b(xv - (float)h);
                }
                *(s16x8*)&tb[dh * 1024 +       (lg * 16 + lj) * 8] = hi8;
                *(s16x8*)&tb[dh * 1024 + 512 + (lg * 16 + lj) * 8] = lo8;
            }
        }
        // Q (rows kt*64..+63 == q-tiles 2kt, 2kt+1)
        {
            const float4* gp = (const float4*)(Q + rowbase + (size_t)row * DH + c0);
            const float4 v0 = gp[0], v1 = gp[1], v2 = gp[2], v3 = gp[3];
            const float x[16] = {v0.x,v0.y,v0.z,v0.w, v1.x,v1.y,v1.z,v1.w,
                                 v2.x,v2.y,v2.z,v2.w, v3.x,v3.y,v3.z,v3.w};
            const int qtile = kt * 2 + (row >> 5);
            const int m     = (row >> 4) & 1;
            short* tb = qimg + ((size_t)head * NQT + qtile) * QTILE_SH + m * 2048;
#pragma unroll
            for (int cg = 0; cg < 2; ++cg) {
                const int col0 = c0 + cg * 8;
                const int dh = col0 >> 5, lg = (col0 & 31) >> 3;
                s16x8 hi8, lo8;
#pragma unroll
                for (int j = 0; j < 8; ++j) {
                    const float xv = x[cg * 8 + j];
                    _Float16 h = (_Float16)xv;
                    hi8[j] = __builtin_bit_cast(short, h);
                    lo8[j] = f16b(xv - (float)h);
                }
                *(s16x8*)&tb[dh * 1024 +       (lg * 16 + lj) * 8] = hi8;
                *(s16x8*)&tb[dh * 1024 + 512 + (lg * 16 + lj) * 8] = lo8;
            }
        }
    }
    {   // ---- V frag-pack: thread = (kc = t>>6, lane l = t&63) ----
        const int kc = t >> 6, l = t & 63;
        const int lg = l >> 4, lj = l & 15;
        short* tb = vimg + ((size_t)head * NKT + kt) * KTILE_SH + kc * 2048;
#pragma unroll
        for (int dt = 0; dt < 4; ++dt) {
            s16x8 o;
#pragma unroll
            for (int j = 0; j < 4; ++j) {
                const float xv = V[rowbase + (size_t)(kc * 16 + lg * 4 + j) * DH + dt * 16 + lj];
                _Float16 h = (_Float16)xv;
                o[j]     = __builtin_bit_cast(short, h);
                o[4 + j] = f16b(xv - (float)h);
            }
            *(s16x8*)&tb[dt * 512 + l * 8] = o;
        }
    }
    if (blockIdx.x == 0) {   // pad bitmask: pm[b*64 + key_local] bit kt
        const int b = t >> 6, klc = t & 63;
        unsigned mword = 0;
#pragma unroll
        for (int kt2 = 0; kt2 < NKT; ++kt2)
            mword |= (unsigned)(pad[b * SEQ + kt2 * 64 + klc] & 1) << kt2;
        pm[t] = mword;
    }
}

struct KF { f16x8 h0, l0, h1, l1; };

#define LDKF(dst_, kt_) do {                                                   \
    const short* p_ = kb + (size_t)(kt_) * KTILE_SH;                           \
    dst_.h0 = *(const f16x8*)(p_ +        l * 8);                              \
    dst_.l0 = *(const f16x8*)(p_ +  512 + l * 8);                              \
    dst_.h1 = *(const f16x8*)(p_ + 1024 + l * 8);                              \
    dst_.l1 = *(const f16x8*)(p_ + 1536 + l * 8);                              \
} while (0)

// 12 MFMAs, 3-term split (kh*qh + kh*ql + kl*qh). SAME order in both passes.
#define QK12(kf_, a0_, a1_) do {                                               \
    a0_ = MF32(kf_.h0, qh[0][0], a0_);  a1_ = MF32(kf_.h0, qh[1][0], a1_);     \
    a0_ = MF32(kf_.h0, ql[0][0], a0_);  a1_ = MF32(kf_.h0, ql[1][0], a1_);     \
    a0_ = MF32(kf_.l0, qh[0][0], a0_);  a1_ = MF32(kf_.l0, qh[1][0], a1_);     \
    a0_ = MF32(kf_.h1, qh[0][1], a0_);  a1_ = MF32(kf_.h1, qh[1][1], a1_);     \
    a0_ = MF32(kf_.h1, ql[0][1], a0_);  a1_ = MF32(kf_.h1, ql[1][1], a1_);     \
    a0_ = MF32(kf_.l1, qh[0][1], a0_);  a1_ = MF32(kf_.l1, qh[1][1], a1_);     \
} while (0)

#define P1BODY(kt_, kf_) do {                                                  \
    const short* vp_ = vb + (size_t)(kt_) * KTILE_SH;                          \
    f16x8 vfs_[4];                                                             \
    _Pragma("unroll") for (int dt = 0; dt < 4; ++dt)                           \
        vfs_[dt] = *(const f16x8*)(vp_ + dt * 512 + l * 8);                    \
    f32x4 a0_ = (f32x4){0.f,0.f,0.f,0.f}, a1_ = (f32x4){0.f,0.f,0.f,0.f};      \
    QK12(kf_, a0_, a1_);                                                       \
    const int kab_ = (kt_) * 64 + wk * 16 + lg * 4;                            \
    f16x4 w16_[2];                                                             \
    _Pragma("unroll") for (int m = 0; m < 2; ++m) {                            \
        const f32x4 av_ = m ? a1_ : a0_;                                       \
        const int qg_ = qglob + m * 16;                                        \
        float e_[4];                                                           \
        _Pragma("unroll") for (int r = 0; r < 4; ++r) {                        \
            const int ka_ = kab_ + r;                                          \
            const int pd_ = (int)((pmq[r] >> (kt_)) & 1u);                     \
            const bool msk_ = ((ka_ > qg_) != (pd_ == 1));                     \
            e_[r] = __expf((msk_ ? -8.0e9f : av_[r]) * 0.125f);                \
        }                                                                      \
        rs[m] += (e_[0] + e_[1]) + (e_[2] + e_[3]);                            \
        w16_[m] = (f16x4){(_Float16)e_[0], (_Float16)e_[1],                    \
                          (_Float16)e_[2], (_Float16)e_[3]};                   \
    }                                                                          \
    _Pragma("unroll") for (int dt = 0; dt < 4; ++dt) {                         \
        const f16x4 vh_ = __builtin_shufflevector(vfs_[dt], vfs_[dt], 0,1,2,3);\
        const f16x4 vl_ = __builtin_shufflevector(vfs_[dt], vfs_[dt], 4,5,6,7);\
        ov[0][dt] = MF16(w16_[0], vh_, ov[0][dt]);                             \
        ov[1][dt] = MF16(w16_[1], vh_, ov[1][dt]);                             \
        ov[0][dt] = MF16(w16_[0], vl_, ov[0][dt]);                             \
        ov[1][dt] = MF16(w16_[1], vl_, ov[1][dt]);                             \
    }                                                                          \
} while (0)

#define P2BODY(kt_, kf_) do {                                                  \
    f32x4 a0_ = (f32x4){0.f,0.f,0.f,0.f}, a1_ = (f32x4){0.f,0.f,0.f,0.f};      \
    QK12(kf_, a0_, a1_);                                                       \
    const int kab_ = (kt_) * 64 + wk * 16 + lg * 4;                            \
    _Pragma("unroll") for (int m = 0; m < 2; ++m) {                            \
        const f32x4 av_ = m ? a1_ : a0_;                                       \
        const int qg_ = qglob + m * 16;                                        \
        float e_[4];                                                           \
        _Pragma("unroll") for (int r = 0; r < 4; ++r) {                        \
            const int ka_ = kab_ + r;                                          \
            const int pd_ = (int)((pmq[r] >> (kt_)) & 1u);                     \
            const bool msk_ = ((ka_ > qg_) != (pd_ == 1));                     \
            e_[r] = __expf((msk_ ? -8.0e9f : av_[r]) * 0.125f);                \
        }                                                                      \
        f32x4 w4_;                                                             \
        w4_[0] = e_[0] * invr[m]; w4_[1] = e_[1] * invr[m];                    \
        w4_[2] = e_[2] * invr[m]; w4_[3] = e_[3] * invr[m];                    \
        __builtin_nontemporal_store(w4_, (f32x4*)&out_w[wbm[m] + kab_]);       \
    }                                                                          \
} while (0)

__global__ __launch_bounds__(256, 3) void attn_fwd(
    const short* __restrict__ QI, const short* __restrict__ KI,
    const short* __restrict__ VI, const unsigned* __restrict__ PM,
    float* __restrict__ out_res, float* __restrict__ out_w)
{
    __shared__ float s_op[4][QT][65];    // per-wk O partials (epilogue)
    __shared__ float s_red[QT][4];       // rowsum partials

    const int t = threadIdx.x;
    int bid = blockIdx.x;
    bid = (bid & 7) * (NBLK / 8) + (bid >> 3);       // XCD-chunked swizzle (4096%8==0)

    const int qtile = bid & (NQT - 1);
    const int head  = bid >> 6;                      // b*NH + h
    const int q0    = qtile * QT;
    const size_t hoff = (size_t)head * SEQ * DH;
    const size_t woff = (size_t)head * SEQ * SEQ;

    const int l  = t & 63;
    const int wk = t >> 6;        // wave = 16-key column group 0..3
    const int lj = l & 15;
    const int lg = l >> 4;
    const int qglob = q0 + lj;    // q row for m=0 (lane-local in swapped layout)

    const short* kb  = KI + (size_t)head * NKT * KTILE_SH + wk * 2048;
    const short* vb  = VI + (size_t)head * NKT * KTILE_SH + wk * 2048;
    const short* qbp = QI + ((size_t)head * NQT + qtile) * QTILE_SH;

    // ---- Q fragments straight from the packed image (no LDS) ----
    f16x8 qh[2][2], ql[2][2];
#pragma unroll
    for (int m = 0; m < 2; ++m)
#pragma unroll
        for (int dh = 0; dh < 2; ++dh) {
            qh[m][dh] = *(const f16x8*)(qbp + m * 2048 + dh * 1024 +       l * 8);
            ql[m][dh] = *(const f16x8*)(qbp + m * 2048 + dh * 1024 + 512 + l * 8);
        }

    int pmq[4];
#pragma unroll
    for (int r = 0; r < 4; ++r)
        pmq[r] = PM[(head >> 4) * 64 + wk * 16 + lg * 4 + r];

    // =============== PASS 1: rowsums + PV with unnormalized f16(e) — no barriers ===============
    float rs[2] = {0.f, 0.f};
    f32x4 ov[2][4];
#pragma unroll
    for (int m = 0; m < 2; ++m)
#pragma unroll
        for (int dt = 0; dt < 4; ++dt) ov[m][dt] = (f32x4){0.f,0.f,0.f,0.f};

    KF kfA, kfB;
    LDKF(kfA, 0);
#pragma unroll 1
    for (int it = 0; it < NKT / 2; ++it) {
        const int kt0 = it * 2, kt1 = kt0 + 1;
        LDKF(kfB, kt1);                 // prefetch while body0 computes
        P1BODY(kt0, kfA);
        LDKF(kfA, (kt1 + 1) & (NKT - 1));
        P1BODY(kt1, kfB);
    }

    // ---- rowsum: lane-local q (=lj) -> sum over lg groups, then wk via LDS ----
#pragma unroll
    for (int m = 0; m < 2; ++m) {
        float v = rs[m];
        v += __shfl_xor(v, 16, 64);
        v += __shfl_xor(v, 32, 64);
        rs[m] = v;
    }
    if (lg == 0) {
        s_red[lj][wk]      = rs[0];
        s_red[16 + lj][wk] = rs[1];
    }
    // ---- O partials (unscaled) ----
#pragma unroll
    for (int m = 0; m < 2; ++m)
#pragma unroll
        for (int dt = 0; dt < 4; ++dt)
#pragma unroll
            for (int r = 0; r < 4; ++r)
                s_op[wk][m * 16 + lg * 4 + r][dt * 16 + lj] = ov[m][dt][r];
    __syncthreads();   // the ONLY block barrier

    // ---- final O: combine 4 wk partials, scale by 1/rowsum, store ----
    {
        const int q  = t >> 3;
        const int c0 = (t & 7) * 8;
        const float inv = 1.0f / (s_red[q][0] + s_red[q][1] + s_red[q][2] + s_red[q][3]);
        float4 o0, o1;
        o0.x = (s_op[0][q][c0+0]+s_op[1][q][c0+0]+s_op[2][q][c0+0]+s_op[3][q][c0+0]) * inv;
        o0.y = (s_op[0][q][c0+1]+s_op[1][q][c0+1]+s_op[2][q][c0+1]+s_op[3][q][c0+1]) * inv;
        o0.z = (s_op[0][q][c0+2]+s_op[1][q][c0+2]+s_op[2][q][c0+2]+s_op[3][q][c0+2]) * inv;
        o0.w = (s_op[0][q][c0+3]+s_op[1][q][c0+3]+s_op[2][q][c0+3]+s_op[3][q][c0+3]) * inv;
        o1.x = (s_op[0][q][c0+4]+s_op[1][q][c0+4]+s_op[2][q][c0+4]+s_op[3][q][c0+4]) * inv;
        o1.y = (s_op[0][q][c0+5]+s_op[1][q][c0+5]+s_op[2][q][c0+5]+s_op[3][q][c0+5]) * inv;
        o1.z = (s_op[0][q][c0+6]+s_op[1][q][c0+6]+s_op[2][q][c0+6]+s_op[3][q][c0+6]) * inv;
        o1.w = (s_op[0][q][c0+7]+s_op[1][q][c0+7]+s_op[2][q][c0+7]+s_op[3][q][c0+7]) * inv;
        float* op = out_res + hoff + (size_t)(q0 + q) * DH + c0;
        *(float4*)op       = o0;
        *(float4*)(op + 4) = o1;
    }

    // =============== PASS 2: recompute e (identical), store normalized W — no barriers ===============
    float invr[2];
    invr[0] = 1.0f / (s_red[lj][0]      + s_red[lj][1]      + s_red[lj][2]      + s_red[lj][3]);
    invr[1] = 1.0f / (s_red[16 + lj][0] + s_red[16 + lj][1] + s_red[16 + lj][2] + s_red[16 + lj][3]);
    size_t wbm[2];
    wbm[0] = woff + (size_t)(q0 + lj) * SEQ;
    wbm[1] = woff + (size_t)(q0 + 16 + lj) * SEQ;

    LDKF(kfA, 0);
#pragma unroll 1
    for (int it = 0; it < NKT / 2; ++it) {
        const int kt0 = it * 2, kt1 = kt0 + 1;
        LDKF(kfB, kt1);
        P2BODY(kt0, kfA);
        LDKF(kfA, (kt1 + 1) & (NKT - 1));
        P2BODY(kt1, kfB);
    }
}

extern "C" void kernel_launch(void* const* d_in, const int* in_sizes, int n_in,
                              void* d_out, int out_size, void* d_ws, size_t ws_size,
                              hipStream_t stream) {
    const float* Q   = (const float*)d_in[0];
    const float* K   = (const float*)d_in[1];
    const float* V   = (const float*)d_in[2];
    const int*   pad = (const int*)d_in[3];
    float* out_res = (float*)d_out;
    float* out_w   = out_res + (size_t)NB * NH * SEQ * DH;

    short* qimg = (short*)d_ws;                               // 33.5 MB
    short* kimg = qimg + (size_t)NHEADS * NQT * QTILE_SH;     // 33.5 MB
    short* vimg = kimg + (size_t)NHEADS * NKT * KTILE_SH;     // 33.5 MB
    unsigned* pm = (unsigned*)(vimg + (size_t)NHEADS * NKT * KTILE_SH);  // 1 KB

    prep<<<dim3(NHEADS * NKT), 256, 0, stream>>>(Q, K, V, pad, qimg, kimg, vimg, pm);
    attn_fwd<<<dim3(NBLK), 256, 0, stream>>>(qimg, kimg, vimg, pm, out_res, out_w);
}

// Round 8
// 1280.265 us; speedup vs baseline: 6.0606x; 1.0640x over previous
//
#include <hip/hip_runtime.h>

#define SEQ 2048
#define DH  64
#define NH  16
#define NB  4
#define NHEADS (NB * NH)            // 64
#define NKT 32                      // k-tiles of 64 keys
#define QT  64                      // q-rows per block
#define NQT (SEQ / QT)              // 32 q-tiles per head
#define NBLK (NHEADS * NQT)         // 2048 blocks
#define KTILE_SH 8192               // shorts per K/V tile image (64x64 hi+lo)
#define QTILE_SH 8192               // shorts per Q tile image (64x64 hi+lo)

typedef _Float16 f16x8 __attribute__((ext_vector_type(8)));
typedef _Float16 f16x4 __attribute__((ext_vector_type(4)));
typedef short    s16x8 __attribute__((ext_vector_type(8)));
typedef float    f32x4 __attribute__((ext_vector_type(4)));

#define MF32(a,b,c) __builtin_amdgcn_mfma_f32_16x16x32_f16(a,b,c,0,0,0)
#define MF16(a,b,c) __builtin_amdgcn_mfma_f32_16x16x16f16(a,b,c,0,0,0)

static __device__ __forceinline__ short f16b(float x) {
    _Float16 h = (_Float16)x;
    return __builtin_bit_cast(short, h);
}

// ------------- prep: pack Q,K,V into fragment-ordered f16 hi/lo images -------------
// kimg tile: [kg 4][dh 2][hl 2][lane 64][8]   (A-frag of swapped QK: row=key=lj, k=d)
// qimg tile: [m 4][dh 2][hl 2][lane 64][8]    (B-frag: col=q=lj, k=d) — 64 q-rows/tile
// vimg tile: [kc 4][dt 4][lane 64][hi 4 | lo 4]  (B-frag of PV: col=d=lj, k=lg*4+j)
__global__ __launch_bounds__(256) void prep(
    const float* __restrict__ Q, const float* __restrict__ K,
    const float* __restrict__ V, const int* __restrict__ pad,
    short* __restrict__ qimg, short* __restrict__ kimg,
    short* __restrict__ vimg, unsigned* __restrict__ pm)
{
    const int t    = threadIdx.x;
    const int kt   = blockIdx.x & (NKT - 1);
    const int head = blockIdx.x >> 5;
    const size_t rowbase = ((size_t)head * SEQ + (size_t)kt * 64) * DH;

    {   // ---- K and Q frag-pack: thread owns (row = t>>2, 16 cols) ----
        const int row = t >> 2;
        const int c0  = (t & 3) * 16;
        const int lj  = row & 15;

        // K
        {
            const float4* gp = (const float4*)(K + rowbase + (size_t)row * DH + c0);
            const float4 v0 = gp[0], v1 = gp[1], v2 = gp[2], v3 = gp[3];
            const float x[16] = {v0.x,v0.y,v0.z,v0.w, v1.x,v1.y,v1.z,v1.w,
                                 v2.x,v2.y,v2.z,v2.w, v3.x,v3.y,v3.z,v3.w};
            short* tb = kimg + ((size_t)head * NKT + kt) * KTILE_SH + (row >> 4) * 2048;
#pragma unroll
            for (int cg = 0; cg < 2; ++cg) {
                const int col0 = c0 + cg * 8;
                const int dh = col0 >> 5, lg = (col0 & 31) >> 3;
                s16x8 hi8, lo8;
#pragma unroll
                for (int j = 0; j < 8; ++j) {
                    const float xv = x[cg * 8 + j];
                    _Float16 h = (_Float16)xv;
                    hi8[j] = __builtin_bit_cast(short, h);
                    lo8[j] = f16b(xv - (float)h);
                }
                *(s16x8*)&tb[dh * 1024 +       (lg * 16 + lj) * 8] = hi8;
                *(s16x8*)&tb[dh * 1024 + 512 + (lg * 16 + lj) * 8] = lo8;
            }
        }
        // Q: this block's 64 rows == q-tile kt (QT=64)
        {
            const float4* gp = (const float4*)(Q + rowbase + (size_t)row * DH + c0);
            const float4 v0 = gp[0], v1 = gp[1], v2 = gp[2], v3 = gp[3];
            const float x[16] = {v0.x,v0.y,v0.z,v0.w, v1.x,v1.y,v1.z,v1.w,
                                 v2.x,v2.y,v2.z,v2.w, v3.x,v3.y,v3.z,v3.w};
            const int m = row >> 4;                    // q-subtile 0..3
            short* tb = qimg + ((size_t)head * NQT + kt) * QTILE_SH + m * 2048;
#pragma unroll
            for (int cg = 0; cg < 2; ++cg) {
                const int col0 = c0 + cg * 8;
                const int dh = col0 >> 5, lg = (col0 & 31) >> 3;
                s16x8 hi8, lo8;
#pragma unroll
                for (int j = 0; j < 8; ++j) {
                    const float xv = x[cg * 8 + j];
                    _Float16 h = (_Float16)xv;
                    hi8[j] = __builtin_bit_cast(short, h);
                    lo8[j] = f16b(xv - (float)h);
                }
                *(s16x8*)&tb[dh * 1024 +       (lg * 16 + lj) * 8] = hi8;
                *(s16x8*)&tb[dh * 1024 + 512 + (lg * 16 + lj) * 8] = lo8;
            }
        }
    }
    {   // ---- V frag-pack: thread = (kc = t>>6, lane l = t&63) ----
        const int kc = t >> 6, l = t & 63;
        const int lg = l >> 4, lj = l & 15;
        short* tb = vimg + ((size_t)head * NKT + kt) * KTILE_SH + kc * 2048;
#pragma unroll
        for (int dt = 0; dt < 4; ++dt) {
            s16x8 o;
#pragma unroll
            for (int j = 0; j < 4; ++j) {
                const float xv = V[rowbase + (size_t)(kc * 16 + lg * 4 + j) * DH + dt * 16 + lj];
                _Float16 h = (_Float16)xv;
                o[j]     = __builtin_bit_cast(short, h);
                o[4 + j] = f16b(xv - (float)h);
            }
            *(s16x8*)&tb[dt * 512 + l * 8] = o;
        }
    }
    if (blockIdx.x == 0) {   // pad bitmask: pm[b*64 + key_local] bit kt
        const int b = t >> 6, klc = t & 63;
        unsigned mword = 0;
#pragma unroll
        for (int kt2 = 0; kt2 < NKT; ++kt2)
            mword |= (unsigned)(pad[b * SEQ + kt2 * 64 + klc] & 1) << kt2;
        pm[t] = mword;
    }
}

struct KF { f16x8 h0, l0, h1, l1; };
struct VF { f16x8 v0, v1, v2, v3; };

#define LDKF(dst_, kt_) do {                                                   \
    const short* p_ = kb + (size_t)(kt_) * KTILE_SH;                           \
    dst_.h0 = *(const f16x8*)(p_ +        l * 8);                              \
    dst_.l0 = *(const f16x8*)(p_ +  512 + l * 8);                              \
    dst_.h1 = *(const f16x8*)(p_ + 1024 + l * 8);                              \
    dst_.l1 = *(const f16x8*)(p_ + 1536 + l * 8);                              \
} while (0)

#define LDVF(dst_, kt_) do {                                                   \
    const short* p_ = vb + (size_t)(kt_) * KTILE_SH;                           \
    dst_.v0 = *(const f16x8*)(p_ +        l * 8);                              \
    dst_.v1 = *(const f16x8*)(p_ +  512 + l * 8);                              \
    dst_.v2 = *(const f16x8*)(p_ + 1024 + l * 8);                              \
    dst_.v3 = *(const f16x8*)(p_ + 1536 + l * 8);                              \
} while (0)

// 24 MFMAs, 3-term split (kh*qh + kh*ql + kl*qh), 4 q-subtiles.
// SAME order in both passes (bitwise-equal e).
#define QK24(kf_, a0_, a1_, a2_, a3_) do {                                     \
    a0_ = MF32(kf_.h0, qh[0][0], a0_);  a1_ = MF32(kf_.h0, qh[1][0], a1_);     \
    a2_ = MF32(kf_.h0, qh[2][0], a2_);  a3_ = MF32(kf_.h0, qh[3][0], a3_);     \
    a0_ = MF32(kf_.h0, ql[0][0], a0_);  a1_ = MF32(kf_.h0, ql[1][0], a1_);     \
    a2_ = MF32(kf_.h0, ql[2][0], a2_);  a3_ = MF32(kf_.h0, ql[3][0], a3_);     \
    a0_ = MF32(kf_.l0, qh[0][0], a0_);  a1_ = MF32(kf_.l0, qh[1][0], a1_);     \
    a2_ = MF32(kf_.l0, qh[2][0], a2_);  a3_ = MF32(kf_.l0, qh[3][0], a3_);     \
    a0_ = MF32(kf_.h1, qh[0][1], a0_);  a1_ = MF32(kf_.h1, qh[1][1], a1_);     \
    a2_ = MF32(kf_.h1, qh[2][1], a2_);  a3_ = MF32(kf_.h1, qh[3][1], a3_);     \
    a0_ = MF32(kf_.h1, ql[0][1], a0_);  a1_ = MF32(kf_.h1, ql[1][1], a1_);     \
    a2_ = MF32(kf_.h1, ql[2][1], a2_);  a3_ = MF32(kf_.h1, ql[3][1], a3_);     \
    a0_ = MF32(kf_.l1, qh[0][1], a0_);  a1_ = MF32(kf_.l1, qh[1][1], a1_);     \
    a2_ = MF32(kf_.l1, qh[2][1], a2_);  a3_ = MF32(kf_.l1, qh[3][1], a3_);     \
} while (0)

#define P1BODY(kt_, kf_, vf_) do {                                             \
    f32x4 a0_ = (f32x4){0.f,0.f,0.f,0.f}, a1_ = (f32x4){0.f,0.f,0.f,0.f};      \
    f32x4 a2_ = (f32x4){0.f,0.f,0.f,0.f}, a3_ = (f32x4){0.f,0.f,0.f,0.f};      \
    QK24(kf_, a0_, a1_, a2_, a3_);                                             \
    const int kab_ = (kt_) * 64 + wk * 16 + lg * 4;                            \
    f16x4 w16_[4];                                                             \
    _Pragma("unroll") for (int m = 0; m < 4; ++m) {                            \
        const f32x4 av_ = (m==0) ? a0_ : (m==1) ? a1_ : (m==2) ? a2_ : a3_;    \
        const int qg_ = qglob + m * 16;                                        \
        float e_[4];                                                           \
        _Pragma("unroll") for (int r = 0; r < 4; ++r) {                        \
            const int ka_ = kab_ + r;                                          \
            const int pd_ = (int)((pmq[r] >> (kt_)) & 1u);                     \
            const bool msk_ = ((ka_ > qg_) != (pd_ == 1));                     \
            e_[r] = __expf((msk_ ? -8.0e9f : av_[r]) * 0.125f);                \
        }                                                                      \
        rs[m] += (e_[0] + e_[1]) + (e_[2] + e_[3]);                            \
        w16_[m] = (f16x4){(_Float16)e_[0], (_Float16)e_[1],                    \
                          (_Float16)e_[2], (_Float16)e_[3]};                   \
    }                                                                          \
    _Pragma("unroll") for (int dt = 0; dt < 4; ++dt) {                         \
        const f16x8 vv_ = (dt==0) ? vf_.v0 : (dt==1) ? vf_.v1                  \
                        : (dt==2) ? vf_.v2 : vf_.v3;                           \
        const f16x4 vh_ = __builtin_shufflevector(vv_, vv_, 0,1,2,3);          \
        const f16x4 vl_ = __builtin_shufflevector(vv_, vv_, 4,5,6,7);          \
        ov[0][dt] = MF16(w16_[0], vh_, ov[0][dt]);                             \
        ov[1][dt] = MF16(w16_[1], vh_, ov[1][dt]);                             \
        ov[2][dt] = MF16(w16_[2], vh_, ov[2][dt]);                             \
        ov[3][dt] = MF16(w16_[3], vh_, ov[3][dt]);                             \
        ov[0][dt] = MF16(w16_[0], vl_, ov[0][dt]);                             \
        ov[1][dt] = MF16(w16_[1], vl_, ov[1][dt]);                             \
        ov[2][dt] = MF16(w16_[2], vl_, ov[2][dt]);                             \
        ov[3][dt] = MF16(w16_[3], vl_, ov[3][dt]);                             \
    }                                                                          \
} while (0)

#define P2BODY(kt_, kf_) do {                                                  \
    f32x4 a0_ = (f32x4){0.f,0.f,0.f,0.f}, a1_ = (f32x4){0.f,0.f,0.f,0.f};      \
    f32x4 a2_ = (f32x4){0.f,0.f,0.f,0.f}, a3_ = (f32x4){0.f,0.f,0.f,0.f};      \
    QK24(kf_, a0_, a1_, a2_, a3_);                                             \
    const int kab_ = (kt_) * 64 + wk * 16 + lg * 4;                            \
    _Pragma("unroll") for (int m = 0; m < 4; ++m) {                            \
        const f32x4 av_ = (m==0) ? a0_ : (m==1) ? a1_ : (m==2) ? a2_ : a3_;    \
        const int qg_ = qglob + m * 16;                                        \
        float e_[4];                                                           \
        _Pragma("unroll") for (int r = 0; r < 4; ++r) {                        \
            const int ka_ = kab_ + r;                                          \
            const int pd_ = (int)((pmq[r] >> (kt_)) & 1u);                     \
            const bool msk_ = ((ka_ > qg_) != (pd_ == 1));                     \
            e_[r] = __expf((msk_ ? -8.0e9f : av_[r]) * 0.125f);                \
        }                                                                      \
        f32x4 w4_;                                                             \
        w4_[0] = e_[0] * invr[m]; w4_[1] = e_[1] * invr[m];                    \
        w4_[2] = e_[2] * invr[m]; w4_[3] = e_[3] * invr[m];                    \
        __builtin_nontemporal_store(w4_, (f32x4*)&out_w[wbm[m] + kab_]);       \
    }                                                                          \
} while (0)

__global__ __launch_bounds__(256, 2) void attn_fwd(
    const short* __restrict__ QI, const short* __restrict__ KI,
    const short* __restrict__ VI, const unsigned* __restrict__ PM,
    float* __restrict__ out_res, float* __restrict__ out_w)
{
    __shared__ float s_op[4][QT][65];    // per-wk O partials (epilogue) ~66.6 KB
    __shared__ float s_red[QT][4];       // rowsum partials

    const int t = threadIdx.x;
    int bid = blockIdx.x;
    bid = (bid & 7) * (NBLK / 8) + (bid >> 3);       // XCD-chunked swizzle (2048%8==0)

    const int qtile = bid & (NQT - 1);
    const int head  = bid >> 5;                      // b*NH + h
    const int q0    = qtile * QT;
    const size_t hoff = (size_t)head * SEQ * DH;
    const size_t woff = (size_t)head * SEQ * SEQ;

    const int l  = t & 63;
    const int wk = t >> 6;        // wave = 16-key column group 0..3
    const int lj = l & 15;
    const int lg = l >> 4;
    const int qglob = q0 + lj;    // q row for m=0 (lane-local in swapped layout)

    const short* kb  = KI + (size_t)head * NKT * KTILE_SH + wk * 2048;
    const short* vb  = VI + (size_t)head * NKT * KTILE_SH + wk * 2048;
    const short* qbp = QI + ((size_t)head * NQT + qtile) * QTILE_SH;

    // ---- Q fragments straight from the packed image (no LDS) ----
    f16x8 qh[4][2], ql[4][2];
#pragma unroll
    for (int m = 0; m < 4; ++m)
#pragma unroll
        for (int dh = 0; dh < 2; ++dh) {
            qh[m][dh] = *(const f16x8*)(qbp + m * 2048 + dh * 1024 +       l * 8);
            ql[m][dh] = *(const f16x8*)(qbp + m * 2048 + dh * 1024 + 512 + l * 8);
        }

    int pmq[4];
#pragma unroll
    for (int r = 0; r < 4; ++r)
        pmq[r] = PM[(head >> 4) * 64 + wk * 16 + lg * 4 + r];

    // =============== PASS 1: rowsums + PV with unnormalized f16(e) — no barriers ===============
    float rs[4] = {0.f, 0.f, 0.f, 0.f};
    f32x4 ov[4][4];
#pragma unroll
    for (int m = 0; m < 4; ++m)
#pragma unroll
        for (int dt = 0; dt < 4; ++dt) ov[m][dt] = (f32x4){0.f,0.f,0.f,0.f};

    KF kfA, kfB;
    VF vfA, vfB;
    LDKF(kfA, 0);
    LDVF(vfA, 0);
#pragma unroll 1
    for (int it = 0; it < NKT / 2; ++it) {
        const int kt0 = it * 2, kt1 = kt0 + 1;
        LDKF(kfB, kt1);                 // prefetch next tile while body0 computes
        LDVF(vfB, kt1);
        P1BODY(kt0, kfA, vfA);
        LDKF(kfA, (kt1 + 1) & (NKT - 1));
        LDVF(vfA, (kt1 + 1) & (NKT - 1));
        P1BODY(kt1, kfB, vfB);
    }

    // ---- rowsum: lane-local q (=lj) -> sum over lg groups, then wk via LDS ----
#pragma unroll
    for (int m = 0; m < 4; ++m) {
        float v = rs[m];
        v += __shfl_xor(v, 16, 64);
        v += __shfl_xor(v, 32, 64);
        rs[m] = v;
    }
    if (lg == 0) {
#pragma unroll
        for (int m = 0; m < 4; ++m)
            s_red[m * 16 + lj][wk] = rs[m];
    }
    // ---- O partials (unscaled) ----
#pragma unroll
    for (int m = 0; m < 4; ++m)
#pragma unroll
        for (int dt = 0; dt < 4; ++dt)
#pragma unroll
            for (int r = 0; r < 4; ++r)
                s_op[wk][m * 16 + lg * 4 + r][dt * 16 + lj] = ov[m][dt][r];
    __syncthreads();   // the ONLY block barrier

    // ---- final O: combine 4 wk partials, scale by 1/rowsum, store ----
    {
        const int q  = t >> 2;
        const int c0 = (t & 3) * 16;
        const float inv = 1.0f / (s_red[q][0] + s_red[q][1] + s_red[q][2] + s_red[q][3]);
        float* op = out_res + hoff + (size_t)(q0 + q) * DH + c0;
#pragma unroll
        for (int g = 0; g < 4; ++g) {
            float4 o;
            o.x = (s_op[0][q][c0+g*4+0]+s_op[1][q][c0+g*4+0]+s_op[2][q][c0+g*4+0]+s_op[3][q][c0+g*4+0]) * inv;
            o.y = (s_op[0][q][c0+g*4+1]+s_op[1][q][c0+g*4+1]+s_op[2][q][c0+g*4+1]+s_op[3][q][c0+g*4+1]) * inv;
            o.z = (s_op[0][q][c0+g*4+2]+s_op[1][q][c0+g*4+2]+s_op[2][q][c0+g*4+2]+s_op[3][q][c0+g*4+2]) * inv;
            o.w = (s_op[0][q][c0+g*4+3]+s_op[1][q][c0+g*4+3]+s_op[2][q][c0+g*4+3]+s_op[3][q][c0+g*4+3]) * inv;
            *(float4*)(op + g * 4) = o;
        }
    }

    // =============== PASS 2: recompute e (identical), store normalized W — no barriers ===============
    float invr[4];
    size_t wbm[4];
#pragma unroll
    for (int m = 0; m < 4; ++m) {
        const int qq = m * 16 + lj;
        invr[m] = 1.0f / (s_red[qq][0] + s_red[qq][1] + s_red[qq][2] + s_red[qq][3]);
        wbm[m]  = woff + (size_t)(q0 + qq) * SEQ;
    }

    LDKF(kfA, 0);
#pragma unroll 1
    for (int it = 0; it < NKT / 2; ++it) {
        const int kt0 = it * 2, kt1 = kt0 + 1;
        LDKF(kfB, kt1);
        P2BODY(kt0, kfA);
        LDKF(kfA, (kt1 + 1) & (NKT - 1));
        P2BODY(kt1, kfB);
    }
}

extern "C" void kernel_launch(void* const* d_in, const int* in_sizes, int n_in,
                              void* d_out, int out_size, void* d_ws, size_t ws_size,
                              hipStream_t stream) {
    const float* Q   = (const float*)d_in[0];
    const float* K   = (const float*)d_in[1];
    const float* V   = (const float*)d_in[2];
    const int*   pad = (const int*)d_in[3];
    float* out_res = (float*)d_out;
    float* out_w   = out_res + (size_t)NB * NH * SEQ * DH;

    short* qimg = (short*)d_ws;                               // 33.5 MB
    short* kimg = qimg + (size_t)NHEADS * NQT * QTILE_SH;     // 33.5 MB
    short* vimg = kimg + (size_t)NHEADS * NKT * KTILE_SH;     // 33.5 MB
    unsigned* pm = (unsigned*)(vimg + (size_t)NHEADS * NKT * KTILE_SH);  // 1 KB

    prep<<<dim3(NHEADS * NKT), 256, 0, stream>>>(Q, K, V, pad, qimg, kimg, vimg, pm);
    attn_fwd<<<dim3(NBLK), 256, 0, stream>>>(qimg, kimg, vimg, pm, out_res, out_w);
}